// Round 5
// baseline (236.021 us; speedup 1.0000x reference)
//
#include <hip/hip_runtime.h>

typedef __bf16 bf16_t;
typedef __bf16 bf16x8 __attribute__((ext_vector_type(8)));
typedef __bf16 bf16x4 __attribute__((ext_vector_type(4)));
typedef float  f32x4  __attribute__((ext_vector_type(4)));
typedef short  short4v __attribute__((ext_vector_type(4)));

#define DEVFN __device__ __forceinline__

DEVFN void gl_lds16(void* lds_base, const void* gsrc) {
  __builtin_amdgcn_global_load_lds(
      (const __attribute__((address_space(1))) void*)gsrc,
      (__attribute__((address_space(3))) void*)lds_base, 16, 0, 0);
}

// swizzled byte offset within a [rows][128B] LDS tile: chunk c of row r lives at c^(r&7)
#define SWZ128(row, bo) (((row) << 7) + ((((bo) >> 4) ^ ((row) & 7)) << 4) + ((bo) & 15))

// ---------------------------------------------------------------- fused converts (+ Vsum zero)
__global__ __launch_bounds__(256) void k_convert_all(
    const float* __restrict__ q, const float* __restrict__ k, const float* __restrict__ v,
    bf16_t* __restrict__ qb, bf16_t* __restrict__ kb, bf16_t* __restrict__ vb,
    float* __restrict__ Vs) {
  if (blockIdx.x == 0) {
    // zero ALL of Vsum (8192 floats) — atomicAdd target, re-zeroed every call
    for (int j = threadIdx.x; j < 8192; j += 256) Vs[j] = 0.f;
  }
  const int NQ = 1572864, NK = 2097152, NT = NQ + 2 * NK;
  int stride = gridDim.x * 256;
  for (int i = blockIdx.x * 256 + threadIdx.x; i < NT; i += stride) {
    const float* src; bf16_t* dst; int off;
    if (i < NQ)           { src = q; dst = qb; off = i; }
    else if (i < NQ + NK) { src = k; dst = kb; off = i - NQ; }
    else                  { src = v; dst = vb; off = i - NQ - NK; }
    float4 vv = reinterpret_cast<const float4*>(src)[off];
    bf16x4 o;
    o[0] = (bf16_t)vv.x; o[1] = (bf16_t)vv.y; o[2] = (bf16_t)vv.z; o[3] = (bf16_t)vv.w;
    reinterpret_cast<bf16x4*>(dst)[off] = o;
  }
}

// ---------------------------------------------------------------- fused weight transposes
__global__ __launch_bounds__(256) void k_transpose_all(
    const float* __restrict__ w_qs, const float* __restrict__ w_ks,
    const float* __restrict__ w_vs, const float* __restrict__ fc_w,
    const float* __restrict__ resid_w,
    bf16_t* __restrict__ wqsT, bf16_t* __restrict__ wksT, bf16_t* __restrict__ wvsT,
    bf16_t* __restrict__ fcwT, bf16_t* __restrict__ rswT) {
  int bid = blockIdx.x;
  const float* w; bf16_t* wt; int K;
  if (bid < 192)      { w = w_qs;    wt = wqsT; K = 768; }
  else if (bid < 448) { w = w_ks;    wt = wksT; K = 1024; bid -= 192; }
  else if (bid < 704) { w = w_vs;    wt = wvsT; K = 1024; bid -= 448; }
  else if (bid < 960) { w = fc_w;    wt = fcwT; K = 1024; bid -= 704; }
  else                { w = resid_w; wt = rswT; K = 768;  bid -= 960; }
  __shared__ float t[64][65];
  const int bk = (bid >> 4) << 6;
  const int bn = (bid & 15) << 6;
  const int rr = threadIdx.x >> 4;
  const int cc = (threadIdx.x & 15) << 2;
#pragma unroll
  for (int i = 0; i < 4; ++i) {
    int r = i * 16 + rr;
    float4 v = *reinterpret_cast<const float4*>(&w[(size_t)(bk + r) * 1024 + bn + cc]);
    t[r][cc] = v.x; t[r][cc + 1] = v.y; t[r][cc + 2] = v.z; t[r][cc + 3] = v.w;
  }
  __syncthreads();
#pragma unroll
  for (int i = 0; i < 4; ++i) {
    int n = i * 16 + rr;
    bf16x4 o;
    o[0] = (bf16_t)t[cc][n];     o[1] = (bf16_t)t[cc + 1][n];
    o[2] = (bf16_t)t[cc + 2][n]; o[3] = (bf16_t)t[cc + 3][n];
    *reinterpret_cast<bf16x4*>(&wt[(size_t)(bn + n) * K + bk + cc]) = o;
  }
}

// ---------------------------------------------------------------- V transpose + column sums
// Vp [B*LK, 1024] bf16 -> Vt as swizzled 8KB tiles [bh][kt]:
//   byte(row=d, k_local) = row*128 + ((k_local>>3)^(row&7))*16
//                        + (((k_local>>2)&1)^((row>>3)&1))*8 + (k_local&3)*2
// This layout makes both the LDS staging copy (linear) and the PV b64 reads
// (all 32 banks once per 16-lane phase) conflict-free.
__global__ __launch_bounds__(256) void k_transpose_v(
    const bf16_t* __restrict__ Vp, bf16_t* __restrict__ Vt, float* __restrict__ Vs) {
  const int kt = blockIdx.x & 15;
  const int bh = blockIdx.x >> 4;
  const int b = bh >> 4, h = bh & 15;
  __shared__ unsigned short t[64][72];
  __shared__ float red[4][64];
#pragma unroll
  for (int i = 0; i < 2; ++i) {
    int cid = i * 256 + threadIdx.x;
    int r = cid >> 3, c = (cid & 7) * 8;
    uint4 v = *reinterpret_cast<const uint4*>(
        Vp + ((size_t)(b * 1024 + kt * 64 + r)) * 1024 + h * 64 + c);
    const unsigned short* pv = reinterpret_cast<const unsigned short*>(&v);
#pragma unroll
    for (int j = 0; j < 8; ++j) t[r][c + j] = pv[j];
  }
  __syncthreads();
#pragma unroll
  for (int i = 0; i < 2; ++i) {
    int cid = i * 256 + threadIdx.x;
    int d = cid >> 3, c = (cid & 7) * 8;   // writes k_local c..c+7 of row d
    unsigned short tmp[8];
#pragma unroll
    for (int j = 0; j < 8; ++j) tmp[j] = t[c + j][d];
    uint4 w = *reinterpret_cast<uint4*>(tmp);
    if ((d >> 3) & 1) {  // swap 8B halves when row bit3 set
      unsigned tx = w.x, ty = w.y;
      w.x = w.z; w.y = w.w; w.z = tx; w.w = ty;
    }
    char* dst = (char*)Vt + ((size_t)(bh * 16 + kt)) * 8192 + d * 128 +
                ((((c >> 3) ^ (d & 7))) << 4);
    *reinterpret_cast<uint4*>(dst) = w;
  }
  const int d = threadIdx.x & 63, seg = threadIdx.x >> 6;
  float s = 0.f;
#pragma unroll
  for (int i = 0; i < 16; ++i)
    s += (float)*(const bf16_t*)&t[seg * 16 + i][d];
  red[seg][d] = s;
  __syncthreads();
  if (threadIdx.x < 64)
    atomicAdd(&Vs[bh * 64 + threadIdx.x],
              red[0][threadIdx.x] + red[1][threadIdx.x] + red[2][threadIdx.x] + red[3][threadIdx.x]);
}

// ---------------------------------------------------------------- GEMM: C[M,N] = (A[M,K] * Bt[N,K]^T) * oscale, bf16 out
__global__ __launch_bounds__(256) void k_gemm_bt(
    const bf16_t* __restrict__ A, const bf16_t* __restrict__ Bt,
    bf16_t* __restrict__ C, int N, int K, float oscale) {
  __shared__ bf16_t As[128 * 32];
  __shared__ bf16_t Bs[128 * 32];
  const int bpx = gridDim.x >> 3;
  const int wg = (blockIdx.x & 7) * bpx + (blockIdx.x >> 3);
  const int tn = N >> 7;
  const int m0 = (wg / tn) << 7;
  const int n0 = (wg % tn) << 7;
  const int lane = threadIdx.x & 63;
  const int wv = threadIdx.x >> 6;
  const int wr = (wv >> 1) * 64, wc = (wv & 1) * 64;
  const int lr = lane & 15, lk = lane >> 4;
  const int so0 = wv * 2048 + lane * 16;
  const int so1 = so0 + 1024;
  const int r0 = so0 >> 6, c0 = so0 & 63;
  const int r1 = so1 >> 6, c1 = so1 & 63;
  char* AsB = (char*)As;
  char* BsB = (char*)Bs;
  const char* Apc = (const char*)A;
  const char* Btc = (const char*)Bt;
  f32x4 zro = {0.f, 0.f, 0.f, 0.f};
  f32x4 acc[4][4];
#pragma unroll
  for (int i = 0; i < 4; ++i)
#pragma unroll
    for (int j = 0; j < 4; ++j) acc[i][j] = zro;

  for (int kt = 0; kt < K; kt += 32) {
    gl_lds16(AsB + wv * 2048,        Apc + ((size_t)(m0 + r0) * K + kt) * 2 + c0);
    gl_lds16(AsB + wv * 2048 + 1024, Apc + ((size_t)(m0 + r1) * K + kt) * 2 + c1);
    gl_lds16(BsB + wv * 2048,        Btc + ((size_t)(n0 + r0) * K + kt) * 2 + c0);
    gl_lds16(BsB + wv * 2048 + 1024, Btc + ((size_t)(n0 + r1) * K + kt) * 2 + c1);
    __syncthreads();
    bf16x8 af[4], bfr[4];
#pragma unroll
    for (int i = 0; i < 4; ++i)
      af[i] = *(const bf16x8*)(AsB + (wr + i * 16 + lr) * 64 + lk * 16);
#pragma unroll
    for (int j = 0; j < 4; ++j)
      bfr[j] = *(const bf16x8*)(BsB + (wc + j * 16 + lr) * 64 + lk * 16);
#pragma unroll
    for (int i = 0; i < 4; ++i)
#pragma unroll
      for (int j = 0; j < 4; ++j)
        acc[i][j] = __builtin_amdgcn_mfma_f32_16x16x32_bf16(af[i], bfr[j], acc[i][j], 0, 0, 0);
    __syncthreads();
  }
#pragma unroll
  for (int i = 0; i < 4; ++i)
#pragma unroll
    for (int j = 0; j < 4; ++j)
#pragma unroll
      for (int r = 0; r < 4; ++r)
        C[(size_t)(m0 + wr + i * 16 + lk * 4 + r) * N + n0 + wc + j * 16 + lr] =
            (bf16_t)(acc[i][j][r] * oscale);
}

// Y[M,N] f32 = A1*B1t^T + A2*B2t^T + bias
__global__ __launch_bounds__(256) void k_gemm_final(
    const bf16_t* __restrict__ A1, const bf16_t* __restrict__ B1t, int K1,
    const bf16_t* __restrict__ A2, const bf16_t* __restrict__ B2t, int K2,
    const float* __restrict__ bias, float* __restrict__ Y, int N) {
  __shared__ bf16_t As[128 * 32];
  __shared__ bf16_t Bs[128 * 32];
  const int bpx = gridDim.x >> 3;
  const int wg = (blockIdx.x & 7) * bpx + (blockIdx.x >> 3);
  const int tn = N >> 7;
  const int m0 = (wg / tn) << 7;
  const int n0 = (wg % tn) << 7;
  const int lane = threadIdx.x & 63;
  const int wv = threadIdx.x >> 6;
  const int wr = (wv >> 1) * 64, wc = (wv & 1) * 64;
  const int lr = lane & 15, lk = lane >> 4;
  const int so0 = wv * 2048 + lane * 16;
  const int so1 = so0 + 1024;
  const int r0 = so0 >> 6, c0 = so0 & 63;
  const int r1 = so1 >> 6, c1 = so1 & 63;
  char* AsB = (char*)As;
  char* BsB = (char*)Bs;
  f32x4 zro = {0.f, 0.f, 0.f, 0.f};
  f32x4 acc[4][4];
#pragma unroll
  for (int i = 0; i < 4; ++i)
#pragma unroll
    for (int j = 0; j < 4; ++j) acc[i][j] = zro;

  const bf16_t* Ap[2] = {A1, A2};
  const bf16_t* Bp[2] = {B1t, B2t};
  const int Kp_[2] = {K1, K2};
  for (int ph = 0; ph < 2; ++ph) {
    const char* Apc = (const char*)Ap[ph];
    const char* Btc = (const char*)Bp[ph];
    const int K = Kp_[ph];
    for (int kt = 0; kt < K; kt += 32) {
      gl_lds16(AsB + wv * 2048,        Apc + ((size_t)(m0 + r0) * K + kt) * 2 + c0);
      gl_lds16(AsB + wv * 2048 + 1024, Apc + ((size_t)(m0 + r1) * K + kt) * 2 + c1);
      gl_lds16(BsB + wv * 2048,        Btc + ((size_t)(n0 + r0) * K + kt) * 2 + c0);
      gl_lds16(BsB + wv * 2048 + 1024, Btc + ((size_t)(n0 + r1) * K + kt) * 2 + c1);
      __syncthreads();
      bf16x8 af[4], bfr[4];
#pragma unroll
      for (int i = 0; i < 4; ++i)
        af[i] = *(const bf16x8*)(AsB + (wr + i * 16 + lr) * 64 + lk * 16);
#pragma unroll
      for (int j = 0; j < 4; ++j)
        bfr[j] = *(const bf16x8*)(BsB + (wc + j * 16 + lr) * 64 + lk * 16);
#pragma unroll
      for (int i = 0; i < 4; ++i)
#pragma unroll
        for (int j = 0; j < 4; ++j)
          acc[i][j] = __builtin_amdgcn_mfma_f32_16x16x32_bf16(af[i], bfr[j], acc[i][j], 0, 0, 0);
      __syncthreads();
    }
  }
#pragma unroll
  for (int i = 0; i < 4; ++i)
#pragma unroll
    for (int j = 0; j < 4; ++j) {
      float bv = bias[n0 + wc + j * 16 + lr];
#pragma unroll
      for (int r = 0; r < 4; ++r)
        Y[(size_t)(m0 + wr + i * 16 + lk * 4 + r) * N + n0 + wc + j * 16 + lr] =
            acc[i][j][r] + bv;
    }
}

// ---------------------------------------------------------------- attention
// out = (Vsum - softmax(QK^T/8) V) / 1023.  Q pre-scaled by 1/8; softmax-lite.
// Swapped QK^T → lane-local P rows → in-register PV via mfma_16x16x16bf16_1k.
// V tiles pre-swizzled in global (see k_transpose_v) → linear staging,
// conflict-free b64 fragment reads. Q fragments loaded straight from global.
__global__ __launch_bounds__(256) void k_attn(
    const bf16_t* __restrict__ Qp, const bf16_t* __restrict__ Kp,
    const bf16_t* __restrict__ Vt, const float* __restrict__ Vsum,
    bf16_t* __restrict__ Aout) {
  const int bid = blockIdx.x;
  const int wgid = (bid & 7) * 256 + (bid >> 3);   // XCD-grouping
  const int qt = wgid & 15;
  const int bh = wgid >> 4;
  const int b = bh >> 4, h = bh & 15;
  __shared__ bf16_t Ks[2][64 * 64];
  __shared__ bf16_t Vs[2][64 * 64];
  const int lane = threadIdx.x & 63;
  const int wv = threadIdx.x >> 6;
  const int lr = lane & 15, lk = lane >> 4;

  const int o0 = wv * 2048 + lane * 16;
  const int o1 = o0 + 1024;
  const int row0 = o0 >> 7, row1 = o1 >> 7;
  const int sc0 = ((((o0 >> 4) & 7) ^ (row0 & 7)) << 4);
  const int sc1 = ((((o1 >> 4) & 7) ^ (row1 & 7)) << 4);

  const char* Ksrc0 = (const char*)(Kp + ((size_t)(b * 1024 + row0)) * 1024 + h * 64) + sc0;
  const char* Ksrc1 = (const char*)(Kp + ((size_t)(b * 1024 + row1)) * 1024 + h * 64) + sc1;
  // V: linear tiled source (layout pre-baked in global)
  const char* Vtile = (const char*)Vt + (size_t)bh * 16 * 8192 + o0;

  // prologue: stage K/V tile 0; load Q fragments straight from global
  gl_lds16((char*)&Ks[0][0] + o0, Ksrc0);
  gl_lds16((char*)&Ks[0][0] + o1 - 1024 + 1024, Ksrc1);  // = +o1
  gl_lds16((char*)&Vs[0][0] + o0, Vtile);
  gl_lds16((char*)&Vs[0][0] + o1, Vtile + 1024);

  bf16x8 qa[2];
  {
    const char* qsrc = (const char*)(Qp + ((size_t)(b * 1024 + qt * 64 + wv * 16 + lr)) * 1024 + h * 64);
    qa[0] = *(const bf16x8*)(qsrc + lk * 16);        // d = lk*8..+7
    qa[1] = *(const bf16x8*)(qsrc + 64 + lk * 16);   // d = 32+lk*8..+7
  }
  __syncthreads();

  // loop-invariant LDS read offsets (bank-conflict-free patterns)
  const int kb0 = lr * 128 + (((lk) ^ (lr & 7)) << 4);        // K chunk ks=0
  const int kb1 = lr * 128 + (((4 + lk) ^ (lr & 7)) << 4);    // K chunk ks=1
  const int vbase = lr * 128 + (((lk & 1) ^ (lr >> 3)) << 3); // V half-select
  int gsw[4];
#pragma unroll
  for (int g = 0; g < 4; ++g)
    gsw[g] = (((2 * g + (lk >> 1)) ^ (lr & 7)) << 4);

  f32x4 zro = {0.f, 0.f, 0.f, 0.f};
  f32x4 oacc[4];
#pragma unroll
  for (int g = 0; g < 4; ++g) oacc[g] = zro;
  float ps = 0.f;   // partial row-sum for q = lr (lane-local)

  for (int kt = 0; kt < 16; ++kt) {
    const int cur = kt & 1;
    char* KsB = (char*)&Ks[cur][0];
    char* VsB = (char*)&Vs[cur][0];
    if (kt < 15) {
      char* KsN = (char*)&Ks[cur ^ 1][0];
      char* VsN = (char*)&Vs[cur ^ 1][0];
      const size_t koff = (size_t)(kt + 1) * 131072;  // 64 rows * 2048 B
      const size_t voff = (size_t)(kt + 1) * 8192;    // next 8KB tile
      gl_lds16(KsN + o0, Ksrc0 + koff);
      gl_lds16(KsN + o1, Ksrc1 + koff);
      gl_lds16(VsN + o0, Vtile + voff);
      gl_lds16(VsN + o1, Vtile + voff + 1024);
    }

    // S^T = K Q^T : sacc[g][r] = S[q=lr][k = g*16 + lk*4 + r]
    f32x4 sacc[4];
#pragma unroll
    for (int g = 0; g < 4; ++g) sacc[g] = zro;
#pragma unroll
    for (int g = 0; g < 4; ++g) {
      bf16x8 kbv = *(const bf16x8*)(KsB + kb0 + g * 2048);
      sacc[g] = __builtin_amdgcn_mfma_f32_16x16x32_bf16(kbv, qa[0], sacc[g], 0, 0, 0);
    }
#pragma unroll
    for (int g = 0; g < 4; ++g) {
      bf16x8 kbv = *(const bf16x8*)(KsB + kb1 + g * 2048);
      sacc[g] = __builtin_amdgcn_mfma_f32_16x16x32_bf16(kbv, qa[1], sacc[g], 0, 0, 0);
    }

    // exp + pack P in-register (A-frag of 16x16x16: lane holds P[q=lr][k=lk*4+j])
    short4v pa_s[4];
#pragma unroll
    for (int g = 0; g < 4; ++g) {
      bf16x4 pw;
#pragma unroll
      for (int r = 0; r < 4; ++r) {
        float p = __expf(sacc[g][r]);
        ps += p;
        pw[r] = (bf16_t)p;
      }
      pa_s[g] = __builtin_bit_cast(short4v, pw);
    }
    // O += P V : 16 x16x16 MFMAs, V b64 fragments (conflict-free swizzle)
#pragma unroll
    for (int g = 0; g < 4; ++g)
#pragma unroll
      for (int gd = 0; gd < 4; ++gd) {
        short4v vbv = *(const short4v*)(VsB + vbase + gsw[g] + gd * 2048);
        oacc[gd] = __builtin_amdgcn_mfma_f32_16x16x16bf16_1k(pa_s[g], vbv, oacc[gd], 0, 0, 0);
      }
    __syncthreads();
  }

  // epilogue: total row-sums. ps holds partial for q=lr; reduce across lk lanes.
  float stot = ps;
  stot += __shfl_xor(stot, 16, 64);
  stot += __shfl_xor(stot, 32, 64);
  float lsum_q[4];
#pragma unroll
  for (int r = 0; r < 4; ++r) lsum_q[r] = __shfl(stot, lk * 4 + r, 64);

#pragma unroll
  for (int gd = 0; gd < 4; ++gd)
#pragma unroll
    for (int r = 0; r < 4; ++r) {
      int d = gd * 16 + lr;
      int qrow = qt * 64 + wv * 16 + lk * 4 + r;
      float attnv = oacc[gd][r] / lsum_q[r];
      float val = (Vsum[bh * 64 + d] - attnv) * (1.0f / 1023.0f);
      Aout[((size_t)(b * 1024 + qrow)) * 1024 + h * 64 + d] = (bf16_t)val;
    }
}

// ---------------------------------------------------------------- layernorm
__global__ __launch_bounds__(256) void k_ln(
    const float* __restrict__ Y, const float* __restrict__ gamma,
    const float* __restrict__ beta, float* __restrict__ out) {
  const int row = blockIdx.x, tid = threadIdx.x;
  const float4 x = reinterpret_cast<const float4*>(Y + (size_t)row * 1024)[tid];
  float s = x.x + x.y + x.z + x.w;
  float q = x.x * x.x + x.y * x.y + x.z * x.z + x.w * x.w;
#pragma unroll
  for (int off = 32; off > 0; off >>= 1) {
    s += __shfl_xor(s, off, 64);
    q += __shfl_xor(q, off, 64);
  }
  __shared__ float ss[4], qs[4];
  if ((tid & 63) == 0) { ss[tid >> 6] = s; qs[tid >> 6] = q; }
  __syncthreads();
  s = ss[0] + ss[1] + ss[2] + ss[3];
  q = qs[0] + qs[1] + qs[2] + qs[3];
  float mean = s * (1.f / 1024.f);
  float var = q * (1.f / 1024.f) - mean * mean;
  float rstd = rsqrtf(var + 1e-5f);
  float4 g = reinterpret_cast<const float4*>(gamma)[tid];
  float4 bt = reinterpret_cast<const float4*>(beta)[tid];
  float4 o;
  o.x = (x.x - mean) * rstd * g.x + bt.x;
  o.y = (x.y - mean) * rstd * g.y + bt.y;
  o.z = (x.z - mean) * rstd * g.z + bt.z;
  o.w = (x.w - mean) * rstd * g.w + bt.w;
  reinterpret_cast<float4*>(out + (size_t)row * 1024)[tid] = o;
}

// ---------------------------------------------------------------- launch
extern "C" void kernel_launch(void* const* d_in, const int* in_sizes, int n_in,
                              void* d_out, int out_size, void* d_ws, size_t ws_size,
                              hipStream_t stream) {
  (void)in_sizes; (void)n_in; (void)out_size;
  const float* q       = (const float*)d_in[0];
  const float* k       = (const float*)d_in[1];
  const float* v       = (const float*)d_in[2];
  const float* w_qs    = (const float*)d_in[3];
  const float* w_ks    = (const float*)d_in[4];
  const float* w_vs    = (const float*)d_in[5];
  const float* fc_w    = (const float*)d_in[6];
  const float* resid_w = (const float*)d_in[7];
  const float* resid_b = (const float*)d_in[8];
  const float* ln_g    = (const float*)d_in[9];
  const float* ln_b    = (const float*)d_in[10];
  float* out = (float*)d_out;
  char* ws = (char*)d_ws;

  if (ws_size < (size_t)122716160) return;  // need ~117 MB

  bf16_t* qb   = (bf16_t*)(ws + 0);
  bf16_t* kb   = (bf16_t*)(ws + 12582912);
  bf16_t* vb   = (bf16_t*)(ws + 29360128);
  float*  Y    = (float*)(ws + 12582912);   // aliases kb+vb (dead after projections)
  bf16_t* wqsT = (bf16_t*)(ws + 46137344);
  bf16_t* wksT = (bf16_t*)(ws + 47710208);
  bf16_t* wvsT = (bf16_t*)(ws + 49807360);
  bf16_t* fcwT = (bf16_t*)(ws + 51904512);
  bf16_t* rswT = (bf16_t*)(ws + 54001664);
  bf16_t* Qp   = (bf16_t*)(ws + 55574528);
  bf16_t* Kp   = (bf16_t*)(ws + 72351744);
  bf16_t* Vp   = (bf16_t*)(ws + 89128960);
  bf16_t* Aout = (bf16_t*)(ws + 89128960);  // aliases Vp (dead after transpose_v)
  bf16_t* VtT  = (bf16_t*)(ws + 105906176);
  float*  Vsm  = (float*)(ws + 122683392);

  k_convert_all<<<2048, 256, 0, stream>>>(q, k, v, qb, kb, vb, Vsm);
  k_transpose_all<<<1152, 256, 0, stream>>>(w_qs, w_ks, w_vs, fc_w, resid_w,
                                            wqsT, wksT, wvsT, fcwT, rswT);
  k_gemm_bt<<<512, 256, 0, stream>>>(qb, wqsT, Qp, 1024, 768, 0.125f);
  k_gemm_bt<<<512, 256, 0, stream>>>(kb, wksT, Kp, 1024, 1024, 1.0f);
  k_gemm_bt<<<512, 256, 0, stream>>>(vb, wvsT, Vp, 1024, 1024, 1.0f);
  k_transpose_v<<<2048, 256, 0, stream>>>(Vp, VtT, Vsm);
  k_attn<<<2048, 256, 0, stream>>>(Qp, Kp, VtT, Vsm, Aout);
  k_gemm_final<<<512, 256, 0, stream>>>(Aout, fcwT, 1024, qb, rswT, 768, resid_b, Y, 1024);
  k_ln<<<8192, 256, 0, stream>>>(Y, ln_g, ln_b, out);
}

// Round 6
// 205.731 us; speedup vs baseline: 1.1472x; 1.1472x over previous
//
#include <hip/hip_runtime.h>

typedef __bf16 bf16_t;
typedef __bf16 bf16x8 __attribute__((ext_vector_type(8)));
typedef __bf16 bf16x4 __attribute__((ext_vector_type(4)));
typedef float  f32x4  __attribute__((ext_vector_type(4)));
typedef short  short4v __attribute__((ext_vector_type(4)));

#if __has_builtin(__builtin_amdgcn_exp2f)
#define EXP2(x) __builtin_amdgcn_exp2f(x)
#else
#define EXP2(x) exp2f(x)
#endif

#define DEVFN __device__ __forceinline__

DEVFN void gl_lds16(void* lds_base, const void* gsrc) {
  __builtin_amdgcn_global_load_lds(
      (const __attribute__((address_space(1))) void*)gsrc,
      (__attribute__((address_space(3))) void*)lds_base, 16, 0, 0);
}

// ---------------------------------------------------------------- fused converts (+ Vsum zero)
__global__ __launch_bounds__(256) void k_convert_all(
    const float* __restrict__ q, const float* __restrict__ k, const float* __restrict__ v,
    bf16_t* __restrict__ qb, bf16_t* __restrict__ kb, bf16_t* __restrict__ vb,
    float* __restrict__ Vs) {
  if (blockIdx.x == 0) {
    for (int j = threadIdx.x; j < 8192; j += 256) Vs[j] = 0.f;  // atomic target: re-zero every call
  }
  const int NQ = 1572864, NK = 2097152, NT = NQ + 2 * NK;
  int stride = gridDim.x * 256;
  for (int i = blockIdx.x * 256 + threadIdx.x; i < NT; i += stride) {
    const float* src; bf16_t* dst; int off;
    if (i < NQ)           { src = q; dst = qb; off = i; }
    else if (i < NQ + NK) { src = k; dst = kb; off = i - NQ; }
    else                  { src = v; dst = vb; off = i - NQ - NK; }
    float4 vv = reinterpret_cast<const float4*>(src)[off];
    bf16x4 o;
    o[0] = (bf16_t)vv.x; o[1] = (bf16_t)vv.y; o[2] = (bf16_t)vv.z; o[3] = (bf16_t)vv.w;
    reinterpret_cast<bf16x4*>(dst)[off] = o;
  }
}

// ---------------------------------------------------------------- fused weight transposes
__global__ __launch_bounds__(256) void k_transpose_all(
    const float* __restrict__ w_qs, const float* __restrict__ w_ks,
    const float* __restrict__ w_vs, const float* __restrict__ fc_w,
    const float* __restrict__ resid_w,
    bf16_t* __restrict__ wqsT, bf16_t* __restrict__ wksT, bf16_t* __restrict__ wvsT,
    bf16_t* __restrict__ fcwT, bf16_t* __restrict__ rswT) {
  int bid = blockIdx.x;
  const float* w; bf16_t* wt; int K;
  if (bid < 192)      { w = w_qs;    wt = wqsT; K = 768; }
  else if (bid < 448) { w = w_ks;    wt = wksT; K = 1024; bid -= 192; }
  else if (bid < 704) { w = w_vs;    wt = wvsT; K = 1024; bid -= 448; }
  else if (bid < 960) { w = fc_w;    wt = fcwT; K = 1024; bid -= 704; }
  else                { w = resid_w; wt = rswT; K = 768;  bid -= 960; }
  __shared__ float t[64][65];
  const int bk = (bid >> 4) << 6;
  const int bn = (bid & 15) << 6;
  const int rr = threadIdx.x >> 4;
  const int cc = (threadIdx.x & 15) << 2;
#pragma unroll
  for (int i = 0; i < 4; ++i) {
    int r = i * 16 + rr;
    float4 v = *reinterpret_cast<const float4*>(&w[(size_t)(bk + r) * 1024 + bn + cc]);
    t[r][cc] = v.x; t[r][cc + 1] = v.y; t[r][cc + 2] = v.z; t[r][cc + 3] = v.w;
  }
  __syncthreads();
#pragma unroll
  for (int i = 0; i < 4; ++i) {
    int n = i * 16 + rr;
    bf16x4 o;
    o[0] = (bf16_t)t[cc][n];     o[1] = (bf16_t)t[cc + 1][n];
    o[2] = (bf16_t)t[cc + 2][n]; o[3] = (bf16_t)t[cc + 3][n];
    *reinterpret_cast<bf16x4*>(&wt[(size_t)(bn + n) * K + bk + cc]) = o;
  }
}

// ---------------------------------------------------------------- V transpose + column sums
// Vp [B*LK, 1024] bf16 -> Vt as swizzled 8KB tiles [bh][kt] (see r4 comment)
__global__ __launch_bounds__(256) void k_transpose_v(
    const bf16_t* __restrict__ Vp, bf16_t* __restrict__ Vt, float* __restrict__ Vs) {
  const int kt = blockIdx.x & 15;
  const int bh = blockIdx.x >> 4;
  const int b = bh >> 4, h = bh & 15;
  __shared__ unsigned short t[64][72];
  __shared__ float red[4][64];
#pragma unroll
  for (int i = 0; i < 2; ++i) {
    int cid = i * 256 + threadIdx.x;
    int r = cid >> 3, c = (cid & 7) * 8;
    uint4 v = *reinterpret_cast<const uint4*>(
        Vp + ((size_t)(b * 1024 + kt * 64 + r)) * 1024 + h * 64 + c);
    const unsigned short* pv = reinterpret_cast<const unsigned short*>(&v);
#pragma unroll
    for (int j = 0; j < 8; ++j) t[r][c + j] = pv[j];
  }
  __syncthreads();
#pragma unroll
  for (int i = 0; i < 2; ++i) {
    int cid = i * 256 + threadIdx.x;
    int d = cid >> 3, c = (cid & 7) * 8;
    unsigned short tmp[8];
#pragma unroll
    for (int j = 0; j < 8; ++j) tmp[j] = t[c + j][d];
    uint4 w = *reinterpret_cast<uint4*>(tmp);
    if ((d >> 3) & 1) {
      unsigned tx = w.x, ty = w.y;
      w.x = w.z; w.y = w.w; w.z = tx; w.w = ty;
    }
    char* dst = (char*)Vt + ((size_t)(bh * 16 + kt)) * 8192 + d * 128 +
                ((((c >> 3) ^ (d & 7))) << 4);
    *reinterpret_cast<uint4*>(dst) = w;
  }
  const int d = threadIdx.x & 63, seg = threadIdx.x >> 6;
  float s = 0.f;
#pragma unroll
  for (int i = 0; i < 16; ++i)
    s += (float)*(const bf16_t*)&t[seg * 16 + i][d];
  red[seg][d] = s;
  __syncthreads();
  if (threadIdx.x < 64)
    atomicAdd(&Vs[bh * 64 + threadIdx.x],
              red[0][threadIdx.x] + red[1][threadIdx.x] + red[2][threadIdx.x] + red[3][threadIdx.x]);
}

// ---------------------------------------------------------------- GEMM: C = (A * Bt^T) * oscale, bf16 out
// double-buffered: stage tile t+1 before computing tile t (T3-minimum)
__global__ __launch_bounds__(256) void k_gemm_bt(
    const bf16_t* __restrict__ A, const bf16_t* __restrict__ Bt,
    bf16_t* __restrict__ C, int N, int K, float oscale) {
  __shared__ bf16_t sm[4][4096];  // A0 A1 B0 B1, each 128x32
  const int bpx = gridDim.x >> 3;
  const int wg = (blockIdx.x & 7) * bpx + (blockIdx.x >> 3);
  const int tn = N >> 7;
  const int m0 = (wg / tn) << 7;
  const int n0 = (wg % tn) << 7;
  const int lane = threadIdx.x & 63;
  const int wv = threadIdx.x >> 6;
  const int wr = (wv >> 1) * 64, wc = (wv & 1) * 64;
  const int lr = lane & 15, lk = lane >> 4;
  const int so0 = wv * 2048 + lane * 16;
  const int so1 = so0 + 1024;
  const int r0 = so0 >> 6, c0 = so0 & 63;
  const int r1 = so1 >> 6, c1 = so1 & 63;
  const char* Apc = (const char*)A;
  const char* Btc = (const char*)Bt;
  f32x4 zro = {0.f, 0.f, 0.f, 0.f};
  f32x4 acc[4][4];
#pragma unroll
  for (int i = 0; i < 4; ++i)
#pragma unroll
    for (int j = 0; j < 4; ++j) acc[i][j] = zro;

  const int nk = K >> 5;
  auto stage = [&](int buf, int t) {
    gl_lds16((char*)sm[buf] + wv * 2048,        Apc + ((size_t)(m0 + r0) * K + t * 32) * 2 + c0);
    gl_lds16((char*)sm[buf] + wv * 2048 + 1024, Apc + ((size_t)(m0 + r1) * K + t * 32) * 2 + c1);
    gl_lds16((char*)sm[2 + buf] + wv * 2048,        Btc + ((size_t)(n0 + r0) * K + t * 32) * 2 + c0);
    gl_lds16((char*)sm[2 + buf] + wv * 2048 + 1024, Btc + ((size_t)(n0 + r1) * K + t * 32) * 2 + c1);
  };
  stage(0, 0);
  __syncthreads();
  for (int t = 0; t < nk; ++t) {
    const int cur = t & 1;
    if (t + 1 < nk) stage(cur ^ 1, t + 1);
    const char* AsB = (const char*)sm[cur];
    const char* BsB = (const char*)sm[2 + cur];
    bf16x8 af[4], bfr[4];
#pragma unroll
    for (int i = 0; i < 4; ++i)
      af[i] = *(const bf16x8*)(AsB + (wr + i * 16 + lr) * 64 + lk * 16);
#pragma unroll
    for (int j = 0; j < 4; ++j)
      bfr[j] = *(const bf16x8*)(BsB + (wc + j * 16 + lr) * 64 + lk * 16);
#pragma unroll
    for (int i = 0; i < 4; ++i)
#pragma unroll
      for (int j = 0; j < 4; ++j)
        acc[i][j] = __builtin_amdgcn_mfma_f32_16x16x32_bf16(af[i], bfr[j], acc[i][j], 0, 0, 0);
    __syncthreads();
  }
#pragma unroll
  for (int i = 0; i < 4; ++i)
#pragma unroll
    for (int j = 0; j < 4; ++j)
#pragma unroll
      for (int r = 0; r < 4; ++r)
        C[(size_t)(m0 + wr + i * 16 + lk * 4 + r) * N + n0 + wc + j * 16 + lr] =
            (bf16_t)(acc[i][j][r] * oscale);
}

// Y[M,N] f32 = A1*B1t^T + A2*B2t^T + bias  (double-buffered per phase)
__global__ __launch_bounds__(256) void k_gemm_final(
    const bf16_t* __restrict__ A1, const bf16_t* __restrict__ B1t, int K1,
    const bf16_t* __restrict__ A2, const bf16_t* __restrict__ B2t, int K2,
    const float* __restrict__ bias, float* __restrict__ Y, int N) {
  __shared__ bf16_t sm[4][4096];
  const int bpx = gridDim.x >> 3;
  const int wg = (blockIdx.x & 7) * bpx + (blockIdx.x >> 3);
  const int tn = N >> 7;
  const int m0 = (wg / tn) << 7;
  const int n0 = (wg % tn) << 7;
  const int lane = threadIdx.x & 63;
  const int wv = threadIdx.x >> 6;
  const int wr = (wv >> 1) * 64, wc = (wv & 1) * 64;
  const int lr = lane & 15, lk = lane >> 4;
  const int so0 = wv * 2048 + lane * 16;
  const int so1 = so0 + 1024;
  const int r0 = so0 >> 6, c0 = so0 & 63;
  const int r1 = so1 >> 6, c1 = so1 & 63;
  f32x4 zro = {0.f, 0.f, 0.f, 0.f};
  f32x4 acc[4][4];
#pragma unroll
  for (int i = 0; i < 4; ++i)
#pragma unroll
    for (int j = 0; j < 4; ++j) acc[i][j] = zro;

  const bf16_t* Ap[2] = {A1, A2};
  const bf16_t* Bp[2] = {B1t, B2t};
  const int Kp_[2] = {K1, K2};
  for (int ph = 0; ph < 2; ++ph) {
    const char* Apc = (const char*)Ap[ph];
    const char* Btc = (const char*)Bp[ph];
    const int K = Kp_[ph];
    const int nk = K >> 5;
    auto stage = [&](int buf, int t) {
      gl_lds16((char*)sm[buf] + wv * 2048,        Apc + ((size_t)(m0 + r0) * K + t * 32) * 2 + c0);
      gl_lds16((char*)sm[buf] + wv * 2048 + 1024, Apc + ((size_t)(m0 + r1) * K + t * 32) * 2 + c1);
      gl_lds16((char*)sm[2 + buf] + wv * 2048,        Btc + ((size_t)(n0 + r0) * K + t * 32) * 2 + c0);
      gl_lds16((char*)sm[2 + buf] + wv * 2048 + 1024, Btc + ((size_t)(n0 + r1) * K + t * 32) * 2 + c1);
    };
    stage(0, 0);
    __syncthreads();
    for (int t = 0; t < nk; ++t) {
      const int cur = t & 1;
      if (t + 1 < nk) stage(cur ^ 1, t + 1);
      const char* AsB = (const char*)sm[cur];
      const char* BsB = (const char*)sm[2 + cur];
      bf16x8 af[4], bfr[4];
#pragma unroll
      for (int i = 0; i < 4; ++i)
        af[i] = *(const bf16x8*)(AsB + (wr + i * 16 + lr) * 64 + lk * 16);
#pragma unroll
      for (int j = 0; j < 4; ++j)
        bfr[j] = *(const bf16x8*)(BsB + (wc + j * 16 + lr) * 64 + lk * 16);
#pragma unroll
      for (int i = 0; i < 4; ++i)
#pragma unroll
        for (int j = 0; j < 4; ++j)
          acc[i][j] = __builtin_amdgcn_mfma_f32_16x16x32_bf16(af[i], bfr[j], acc[i][j], 0, 0, 0);
      __syncthreads();
    }
  }
#pragma unroll
  for (int i = 0; i < 4; ++i)
#pragma unroll
    for (int j = 0; j < 4; ++j) {
      float bv = bias[n0 + wc + j * 16 + lr];
#pragma unroll
      for (int r = 0; r < 4; ++r)
        Y[(size_t)(m0 + wr + i * 16 + lk * 4 + r) * N + n0 + wc + j * 16 + lr] =
            acc[i][j][r] + bv;
    }
}

// ---------------------------------------------------------------- attention
// out = (Vsum - softmax(QK^T/8) V) / 1023.  Q pre-scaled by 0.125*log2(e),
// p = 2^s via v_exp_f32.  QBLK=128: 2 q-subtiles per wave share each staged
// K/V tile (K frags + V frags reused) → half the barrier-drain per FLOP.
// Row-sums via ones-MFMA (lands in oacc layout; no shuffles).
__global__ __launch_bounds__(256) void k_attn(
    const bf16_t* __restrict__ Qp, const bf16_t* __restrict__ Kp,
    const bf16_t* __restrict__ Vt, const float* __restrict__ Vsum,
    bf16_t* __restrict__ Aout) {
  const int bid = blockIdx.x;
  const int wgid = (bid & 7) * 128 + (bid >> 3);   // XCD-grouping, 1024 blocks
  const int qg = wgid & 7;                          // 128-row q-group
  const int bh = wgid >> 3;
  const int b = bh >> 4, h = bh & 15;
  __shared__ bf16_t Ks[2][64 * 64];
  __shared__ bf16_t Vs[2][64 * 64];
  const int lane = threadIdx.x & 63;
  const int wv = threadIdx.x >> 6;
  const int lr = lane & 15, lk = lane >> 4;

  const int o0 = wv * 2048 + lane * 16;
  const int o1 = o0 + 1024;
  const int row0 = o0 >> 7, row1 = o1 >> 7;
  const int sc0 = ((((o0 >> 4) & 7) ^ (row0 & 7)) << 4);
  const int sc1 = ((((o1 >> 4) & 7) ^ (row1 & 7)) << 4);

  const char* Ksrc0 = (const char*)(Kp + ((size_t)(b * 1024 + row0)) * 1024 + h * 64) + sc0;
  const char* Ksrc1 = (const char*)(Kp + ((size_t)(b * 1024 + row1)) * 1024 + h * 64) + sc1;
  const char* Vtile = (const char*)Vt + (size_t)bh * 131072 + o0;

  gl_lds16((char*)&Ks[0][0] + o0, Ksrc0);
  gl_lds16((char*)&Ks[0][0] + o1, Ksrc1);
  gl_lds16((char*)&Vs[0][0] + o0, Vtile);
  gl_lds16((char*)&Vs[0][0] + o1, Vtile + 1024);

  bf16x8 qa[2][2];
#pragma unroll
  for (int st = 0; st < 2; ++st) {
    const char* qsrc =
        (const char*)(Qp + ((size_t)(b * 1024 + qg * 128 + st * 64 + wv * 16 + lr)) * 1024 + h * 64);
    qa[st][0] = *(const bf16x8*)(qsrc + lk * 16);
    qa[st][1] = *(const bf16x8*)(qsrc + 64 + lk * 16);
  }
  __syncthreads();

  const int kb0 = lr * 128 + ((lk ^ (lr & 7)) << 4);
  const int kb1 = lr * 128 + (((4 + lk) ^ (lr & 7)) << 4);
  const int vbase = lr * 128 + (((lk & 1) ^ (lr >> 3)) << 3);
  int gsw[4];
#pragma unroll
  for (int g = 0; g < 4; ++g)
    gsw[g] = (((2 * g + (lk >> 1)) ^ (lr & 7)) << 4);

  f32x4 zro = {0.f, 0.f, 0.f, 0.f};
  f32x4 oacc[2][4];
  f32x4 sum[2];
#pragma unroll
  for (int st = 0; st < 2; ++st) {
    sum[st] = zro;
#pragma unroll
    for (int g = 0; g < 4; ++g) oacc[st][g] = zro;
  }
  const short4v ones = {(short)0x3F80, (short)0x3F80, (short)0x3F80, (short)0x3F80};

  for (int kt = 0; kt < 16; ++kt) {
    const int cur = kt & 1;
    const char* KsB = (const char*)&Ks[cur][0];
    const char* VsB = (const char*)&Vs[cur][0];
    if (kt < 15) {
      char* KsN = (char*)&Ks[cur ^ 1][0];
      char* VsN = (char*)&Vs[cur ^ 1][0];
      const size_t koff = (size_t)(kt + 1) * 131072;
      const size_t voff = (size_t)(kt + 1) * 8192;
      gl_lds16(KsN + o0, Ksrc0 + koff);
      gl_lds16(KsN + o1, Ksrc1 + koff);
      gl_lds16(VsN + o0, Vtile + voff);
      gl_lds16(VsN + o1, Vtile + voff + 1024);
    }

    // S^T = K Q^T for both subtiles; K fragments shared
    f32x4 sacc[2][4];
#pragma unroll
    for (int st = 0; st < 2; ++st)
#pragma unroll
      for (int g = 0; g < 4; ++g) sacc[st][g] = zro;
    {
      bf16x8 kf[4];
#pragma unroll
      for (int g = 0; g < 4; ++g) kf[g] = *(const bf16x8*)(KsB + kb0 + g * 2048);
#pragma unroll
      for (int st = 0; st < 2; ++st)
#pragma unroll
        for (int g = 0; g < 4; ++g)
          sacc[st][g] = __builtin_amdgcn_mfma_f32_16x16x32_bf16(kf[g], qa[st][0], sacc[st][g], 0, 0, 0);
#pragma unroll
      for (int g = 0; g < 4; ++g) kf[g] = *(const bf16x8*)(KsB + kb1 + g * 2048);
#pragma unroll
      for (int st = 0; st < 2; ++st)
#pragma unroll
        for (int g = 0; g < 4; ++g)
          sacc[st][g] = __builtin_amdgcn_mfma_f32_16x16x32_bf16(kf[g], qa[st][1], sacc[st][g], 0, 0, 0);
    }

    // p = 2^s, pack to bf16 A-fragments
    short4v pa[2][4];
#pragma unroll
    for (int st = 0; st < 2; ++st)
#pragma unroll
      for (int g = 0; g < 4; ++g) {
        bf16x4 pw;
#pragma unroll
        for (int r = 0; r < 4; ++r) pw[r] = (bf16_t)EXP2(sacc[st][g][r]);
        pa[st][g] = __builtin_bit_cast(short4v, pw);
      }

    // O += P V ; rowsum += P·1 — V fragments shared across subtiles
#pragma unroll
    for (int g = 0; g < 4; ++g) {
      short4v vbv[4];
#pragma unroll
      for (int gd = 0; gd < 4; ++gd)
        vbv[gd] = *(const short4v*)(VsB + vbase + gsw[g] + gd * 2048);
#pragma unroll
      for (int st = 0; st < 2; ++st) {
        sum[st] = __builtin_amdgcn_mfma_f32_16x16x16bf16_1k(pa[st][g], ones, sum[st], 0, 0, 0);
#pragma unroll
        for (int gd = 0; gd < 4; ++gd)
          oacc[st][gd] = __builtin_amdgcn_mfma_f32_16x16x16bf16_1k(pa[st][g], vbv[gd], oacc[st][gd], 0, 0, 0);
      }
    }
    __syncthreads();
  }

  // epilogue — sums already in oacc row layout, lane-local
  float vs_d[4];
#pragma unroll
  for (int gd = 0; gd < 4; ++gd) vs_d[gd] = Vsum[bh * 64 + gd * 16 + lr];
#pragma unroll
  for (int st = 0; st < 2; ++st) {
    float inv[4];
#pragma unroll
    for (int r = 0; r < 4; ++r) inv[r] = 1.0f / sum[st][r];
#pragma unroll
    for (int gd = 0; gd < 4; ++gd)
#pragma unroll
      for (int r = 0; r < 4; ++r) {
        int d = gd * 16 + lr;
        int qrow = qg * 128 + st * 64 + wv * 16 + lk * 4 + r;
        float attnv = oacc[st][gd][r] * inv[r];
        float val = (vs_d[gd] - attnv) * (1.0f / 1023.0f);
        Aout[((size_t)(b * 1024 + qrow)) * 1024 + h * 64 + d] = (bf16_t)val;
      }
  }
}

// ---------------------------------------------------------------- layernorm
__global__ __launch_bounds__(256) void k_ln(
    const float* __restrict__ Y, const float* __restrict__ gamma,
    const float* __restrict__ beta, float* __restrict__ out) {
  const int row = blockIdx.x, tid = threadIdx.x;
  const float4 x = reinterpret_cast<const float4*>(Y + (size_t)row * 1024)[tid];
  float s = x.x + x.y + x.z + x.w;
  float q = x.x * x.x + x.y * x.y + x.z * x.z + x.w * x.w;
#pragma unroll
  for (int off = 32; off > 0; off >>= 1) {
    s += __shfl_xor(s, off, 64);
    q += __shfl_xor(q, off, 64);
  }
  __shared__ float ss[4], qs[4];
  if ((tid & 63) == 0) { ss[tid >> 6] = s; qs[tid >> 6] = q; }
  __syncthreads();
  s = ss[0] + ss[1] + ss[2] + ss[3];
  q = qs[0] + qs[1] + qs[2] + qs[3];
  float mean = s * (1.f / 1024.f);
  float var = q * (1.f / 1024.f) - mean * mean;
  float rstd = rsqrtf(var + 1e-5f);
  float4 g = reinterpret_cast<const float4*>(gamma)[tid];
  float4 bt = reinterpret_cast<const float4*>(beta)[tid];
  float4 o;
  o.x = (x.x - mean) * rstd * g.x + bt.x;
  o.y = (x.y - mean) * rstd * g.y + bt.y;
  o.z = (x.z - mean) * rstd * g.z + bt.z;
  o.w = (x.w - mean) * rstd * g.w + bt.w;
  reinterpret_cast<float4*>(out + (size_t)row * 1024)[tid] = o;
}

// ---------------------------------------------------------------- launch
extern "C" void kernel_launch(void* const* d_in, const int* in_sizes, int n_in,
                              void* d_out, int out_size, void* d_ws, size_t ws_size,
                              hipStream_t stream) {
  (void)in_sizes; (void)n_in; (void)out_size;
  const float* q       = (const float*)d_in[0];
  const float* k       = (const float*)d_in[1];
  const float* v       = (const float*)d_in[2];
  const float* w_qs    = (const float*)d_in[3];
  const float* w_ks    = (const float*)d_in[4];
  const float* w_vs    = (const float*)d_in[5];
  const float* fc_w    = (const float*)d_in[6];
  const float* resid_w = (const float*)d_in[7];
  const float* resid_b = (const float*)d_in[8];
  const float* ln_g    = (const float*)d_in[9];
  const float* ln_b    = (const float*)d_in[10];
  float* out = (float*)d_out;
  char* ws = (char*)d_ws;

  if (ws_size < (size_t)122716160) return;  // need ~117 MB

  bf16_t* qb   = (bf16_t*)(ws + 0);
  bf16_t* kb   = (bf16_t*)(ws + 12582912);
  bf16_t* vb   = (bf16_t*)(ws + 29360128);
  float*  Y    = (float*)(ws + 12582912);   // aliases kb+vb (dead after projections)
  bf16_t* wqsT = (bf16_t*)(ws + 46137344);
  bf16_t* wksT = (bf16_t*)(ws + 47710208);
  bf16_t* wvsT = (bf16_t*)(ws + 49807360);
  bf16_t* fcwT = (bf16_t*)(ws + 51904512);
  bf16_t* rswT = (bf16_t*)(ws + 54001664);
  bf16_t* Qp   = (bf16_t*)(ws + 55574528);
  bf16_t* Kp   = (bf16_t*)(ws + 72351744);
  bf16_t* Vp   = (bf16_t*)(ws + 89128960);
  bf16_t* Aout = (bf16_t*)(ws + 89128960);  // aliases Vp (dead after transpose_v)
  bf16_t* VtT  = (bf16_t*)(ws + 105906176);
  float*  Vsm  = (float*)(ws + 122683392);

  k_convert_all<<<2048, 256, 0, stream>>>(q, k, v, qb, kb, vb, Vsm);
  k_transpose_all<<<1152, 256, 0, stream>>>(w_qs, w_ks, w_vs, fc_w, resid_w,
                                            wqsT, wksT, wvsT, fcwT, rswT);
  // Q pre-scale: 1/8 * log2(e) so scores feed 2^x directly
  k_gemm_bt<<<512, 256, 0, stream>>>(qb, wqsT, Qp, 1024, 768, 0.18033688011f);
  k_gemm_bt<<<512, 256, 0, stream>>>(kb, wksT, Kp, 1024, 1024, 1.0f);
  k_gemm_bt<<<512, 256, 0, stream>>>(vb, wvsT, Vp, 1024, 1024, 1.0f);
  k_transpose_v<<<2048, 256, 0, stream>>>(Vp, VtT, Vsm);
  k_attn<<<1024, 256, 0, stream>>>(Qp, Kp, VtT, Vsm, Aout);
  k_gemm_final<<<512, 256, 0, stream>>>(Aout, fcwT, 1024, qb, rswT, 768, resid_b, Y, 1024);
  k_ln<<<8192, 256, 0, stream>>>(Y, ln_g, ln_b, out);
}

// Round 7
// 198.342 us; speedup vs baseline: 1.1900x; 1.0373x over previous
//
#include <hip/hip_runtime.h>

typedef __bf16 bf16_t;
typedef __bf16 bf16x8 __attribute__((ext_vector_type(8)));
typedef __bf16 bf16x4 __attribute__((ext_vector_type(4)));
typedef float  f32x4  __attribute__((ext_vector_type(4)));

#if __has_builtin(__builtin_amdgcn_exp2f)
#define EXP2(x) __builtin_amdgcn_exp2f(x)
#else
#define EXP2(x) exp2f(x)
#endif

#define DEVFN __device__ __forceinline__

DEVFN void gl_lds16(void* lds_base, const void* gsrc) {
  __builtin_amdgcn_global_load_lds(
      (const __attribute__((address_space(1))) void*)gsrc,
      (__attribute__((address_space(3))) void*)lds_base, 16, 0, 0);
}

// ---------------------------------------------------------------- fused converts (+ Vsum zero)
__global__ __launch_bounds__(256) void k_convert_all(
    const float* __restrict__ q, const float* __restrict__ k, const float* __restrict__ v,
    bf16_t* __restrict__ qb, bf16_t* __restrict__ kb, bf16_t* __restrict__ vb,
    float* __restrict__ Vs) {
  if (blockIdx.x == 0) {
    for (int j = threadIdx.x; j < 8192; j += 256) Vs[j] = 0.f;  // atomic target: re-zero every call
  }
  const int NQ = 1572864, NK = 2097152, NT = NQ + 2 * NK;
  int stride = gridDim.x * 256;
  for (int i = blockIdx.x * 256 + threadIdx.x; i < NT; i += stride) {
    const float* src; bf16_t* dst; int off;
    if (i < NQ)           { src = q; dst = qb; off = i; }
    else if (i < NQ + NK) { src = k; dst = kb; off = i - NQ; }
    else                  { src = v; dst = vb; off = i - NQ - NK; }
    float4 vv = reinterpret_cast<const float4*>(src)[off];
    bf16x4 o;
    o[0] = (bf16_t)vv.x; o[1] = (bf16_t)vv.y; o[2] = (bf16_t)vv.z; o[3] = (bf16_t)vv.w;
    reinterpret_cast<bf16x4*>(dst)[off] = o;
  }
}

// ---------------------------------------------------------------- fused weight transposes
__global__ __launch_bounds__(256) void k_transpose_all(
    const float* __restrict__ w_qs, const float* __restrict__ w_ks,
    const float* __restrict__ w_vs, const float* __restrict__ fc_w,
    const float* __restrict__ resid_w,
    bf16_t* __restrict__ wqsT, bf16_t* __restrict__ wksT, bf16_t* __restrict__ wvsT,
    bf16_t* __restrict__ fcwT, bf16_t* __restrict__ rswT) {
  int bid = blockIdx.x;
  const float* w; bf16_t* wt; int K;
  if (bid < 192)      { w = w_qs;    wt = wqsT; K = 768; }
  else if (bid < 448) { w = w_ks;    wt = wksT; K = 1024; bid -= 192; }
  else if (bid < 704) { w = w_vs;    wt = wvsT; K = 1024; bid -= 448; }
  else if (bid < 960) { w = fc_w;    wt = fcwT; K = 1024; bid -= 704; }
  else                { w = resid_w; wt = rswT; K = 768;  bid -= 960; }
  __shared__ float t[64][65];
  const int bk = (bid >> 4) << 6;
  const int bn = (bid & 15) << 6;
  const int rr = threadIdx.x >> 4;
  const int cc = (threadIdx.x & 15) << 2;
#pragma unroll
  for (int i = 0; i < 4; ++i) {
    int r = i * 16 + rr;
    float4 v = *reinterpret_cast<const float4*>(&w[(size_t)(bk + r) * 1024 + bn + cc]);
    t[r][cc] = v.x; t[r][cc + 1] = v.y; t[r][cc + 2] = v.z; t[r][cc + 3] = v.w;
  }
  __syncthreads();
#pragma unroll
  for (int i = 0; i < 4; ++i) {
    int n = i * 16 + rr;
    bf16x4 o;
    o[0] = (bf16_t)t[cc][n];     o[1] = (bf16_t)t[cc + 1][n];
    o[2] = (bf16_t)t[cc + 2][n]; o[3] = (bf16_t)t[cc + 3][n];
    *reinterpret_cast<bf16x4*>(&wt[(size_t)(bn + n) * K + bk + cc]) = o;
  }
}

// ---------------------------------------------------------------- V transpose + column sums
// Vp [B*LK,1024] -> Vt 8KB tiles [bh][kt], rows=d, 16B-chunk swizzle: chunk c
// of row d stored at c^(d&7). Linear staging + conflict-free b128 reads.
__global__ __launch_bounds__(256) void k_transpose_v(
    const bf16_t* __restrict__ Vp, bf16_t* __restrict__ Vt, float* __restrict__ Vs) {
  const int kt = blockIdx.x & 15;
  const int bh = blockIdx.x >> 4;
  const int b = bh >> 4, h = bh & 15;
  __shared__ unsigned short t[64][72];
  __shared__ float red[4][64];
#pragma unroll
  for (int i = 0; i < 2; ++i) {
    int cid = i * 256 + threadIdx.x;
    int r = cid >> 3, c = (cid & 7) * 8;
    uint4 v = *reinterpret_cast<const uint4*>(
        Vp + ((size_t)(b * 1024 + kt * 64 + r)) * 1024 + h * 64 + c);
    const unsigned short* pv = reinterpret_cast<const unsigned short*>(&v);
#pragma unroll
    for (int j = 0; j < 8; ++j) t[r][c + j] = pv[j];
  }
  __syncthreads();
#pragma unroll
  for (int i = 0; i < 2; ++i) {
    int cid = i * 256 + threadIdx.x;
    int d = cid >> 3, c = (cid & 7) * 8;
    unsigned short tmp[8];
#pragma unroll
    for (int j = 0; j < 8; ++j) tmp[j] = t[c + j][d];
    char* dst = (char*)Vt + ((size_t)(bh * 16 + kt)) * 8192 + d * 128 +
                ((((c >> 3) ^ (d & 7))) << 4);
    *reinterpret_cast<uint4*>(dst) = *reinterpret_cast<uint4*>(tmp);
  }
  const int d = threadIdx.x & 63, seg = threadIdx.x >> 6;
  float s = 0.f;
#pragma unroll
  for (int i = 0; i < 16; ++i)
    s += (float)*(const bf16_t*)&t[seg * 16 + i][d];
  red[seg][d] = s;
  __syncthreads();
  if (threadIdx.x < 64)
    atomicAdd(&Vs[bh * 64 + threadIdx.x],
              red[0][threadIdx.x] + red[1][threadIdx.x] + red[2][threadIdx.x] + red[3][threadIdx.x]);
}

// ---------------------------------------------------------------- GEMM core (double-buffered)
DEVFN void gemm_core(const bf16_t* __restrict__ A, const bf16_t* __restrict__ Bt,
                     bf16_t* __restrict__ C, int N, int K, float oscale,
                     int wg, bf16_t (*sm)[4096]) {
  const int tn = N >> 7;
  const int m0 = (wg / tn) << 7;
  const int n0 = (wg % tn) << 7;
  const int lane = threadIdx.x & 63;
  const int wv = threadIdx.x >> 6;
  const int wr = (wv >> 1) * 64, wc = (wv & 1) * 64;
  const int lr = lane & 15, lk = lane >> 4;
  const int so0 = wv * 2048 + lane * 16;
  const int so1 = so0 + 1024;
  const int r0 = so0 >> 6, c0 = so0 & 63;
  const int r1 = so1 >> 6, c1 = so1 & 63;
  const char* Apc = (const char*)A;
  const char* Btc = (const char*)Bt;
  f32x4 zro = {0.f, 0.f, 0.f, 0.f};
  f32x4 acc[4][4];
#pragma unroll
  for (int i = 0; i < 4; ++i)
#pragma unroll
    for (int j = 0; j < 4; ++j) acc[i][j] = zro;

  const int nk = K >> 5;
  auto stage = [&](int buf, int t) {
    gl_lds16((char*)sm[buf] + wv * 2048,        Apc + ((size_t)(m0 + r0) * K + t * 32) * 2 + c0);
    gl_lds16((char*)sm[buf] + wv * 2048 + 1024, Apc + ((size_t)(m0 + r1) * K + t * 32) * 2 + c1);
    gl_lds16((char*)sm[2 + buf] + wv * 2048,        Btc + ((size_t)(n0 + r0) * K + t * 32) * 2 + c0);
    gl_lds16((char*)sm[2 + buf] + wv * 2048 + 1024, Btc + ((size_t)(n0 + r1) * K + t * 32) * 2 + c1);
  };
  stage(0, 0);
  __syncthreads();
  for (int t = 0; t < nk; ++t) {
    const int cur = t & 1;
    if (t + 1 < nk) stage(cur ^ 1, t + 1);
    const char* AsB = (const char*)sm[cur];
    const char* BsB = (const char*)sm[2 + cur];
    bf16x8 af[4], bfr[4];
#pragma unroll
    for (int i = 0; i < 4; ++i)
      af[i] = *(const bf16x8*)(AsB + (wr + i * 16 + lr) * 64 + lk * 16);
#pragma unroll
    for (int j = 0; j < 4; ++j)
      bfr[j] = *(const bf16x8*)(BsB + (wc + j * 16 + lr) * 64 + lk * 16);
#pragma unroll
    for (int i = 0; i < 4; ++i)
#pragma unroll
      for (int j = 0; j < 4; ++j)
        acc[i][j] = __builtin_amdgcn_mfma_f32_16x16x32_bf16(af[i], bfr[j], acc[i][j], 0, 0, 0);
    __syncthreads();
  }
#pragma unroll
  for (int i = 0; i < 4; ++i)
#pragma unroll
    for (int j = 0; j < 4; ++j)
#pragma unroll
      for (int r = 0; r < 4; ++r)
        C[(size_t)(m0 + wr + i * 16 + lk * 4 + r) * N + n0 + wc + j * 16 + lr] =
            (bf16_t)(acc[i][j][r] * oscale);
}

// fused Q/K/V projections: 1536 blocks, 512 per projection
__global__ __launch_bounds__(256) void k_gemm_proj(
    const bf16_t* __restrict__ qb, const bf16_t* __restrict__ wqsT, bf16_t* __restrict__ Qp,
    const bf16_t* __restrict__ kb, const bf16_t* __restrict__ wksT, bf16_t* __restrict__ Kp,
    const bf16_t* __restrict__ vb, const bf16_t* __restrict__ wvsT, bf16_t* __restrict__ Vp,
    float qscale) {
  __shared__ bf16_t sm[4][4096];
  const int bid = blockIdx.x;
  const int route = bid >> 9;
  const int sbid = bid & 511;
  const int wg = (sbid & 7) * 64 + (sbid >> 3);   // XCD-grouped
  if (route == 0)      gemm_core(qb, wqsT, Qp, 1024, 768,  qscale, wg, sm);
  else if (route == 1) gemm_core(kb, wksT, Kp, 1024, 1024, 1.0f,   wg, sm);
  else                 gemm_core(vb, wvsT, Vp, 1024, 1024, 1.0f,   wg, sm);
}

// Y[M,N] f32 = A1*B1t^T + A2*B2t^T + bias  (double-buffered per phase)
__global__ __launch_bounds__(256) void k_gemm_final(
    const bf16_t* __restrict__ A1, const bf16_t* __restrict__ B1t, int K1,
    const bf16_t* __restrict__ A2, const bf16_t* __restrict__ B2t, int K2,
    const float* __restrict__ bias, float* __restrict__ Y, int N) {
  __shared__ bf16_t sm[4][4096];
  const int bpx = gridDim.x >> 3;
  const int wg = (blockIdx.x & 7) * bpx + (blockIdx.x >> 3);
  const int tn = N >> 7;
  const int m0 = (wg / tn) << 7;
  const int n0 = (wg % tn) << 7;
  const int lane = threadIdx.x & 63;
  const int wv = threadIdx.x >> 6;
  const int wr = (wv >> 1) * 64, wc = (wv & 1) * 64;
  const int lr = lane & 15, lk = lane >> 4;
  const int so0 = wv * 2048 + lane * 16;
  const int so1 = so0 + 1024;
  const int r0 = so0 >> 6, c0 = so0 & 63;
  const int r1 = so1 >> 6, c1 = so1 & 63;
  f32x4 zro = {0.f, 0.f, 0.f, 0.f};
  f32x4 acc[4][4];
#pragma unroll
  for (int i = 0; i < 4; ++i)
#pragma unroll
    for (int j = 0; j < 4; ++j) acc[i][j] = zro;

  const bf16_t* Ap[2] = {A1, A2};
  const bf16_t* Bp[2] = {B1t, B2t};
  const int Kp_[2] = {K1, K2};
  for (int ph = 0; ph < 2; ++ph) {
    const char* Apc = (const char*)Ap[ph];
    const char* Btc = (const char*)Bp[ph];
    const int K = Kp_[ph];
    const int nk = K >> 5;
    auto stage = [&](int buf, int t) {
      gl_lds16((char*)sm[buf] + wv * 2048,        Apc + ((size_t)(m0 + r0) * K + t * 32) * 2 + c0);
      gl_lds16((char*)sm[buf] + wv * 2048 + 1024, Apc + ((size_t)(m0 + r1) * K + t * 32) * 2 + c1);
      gl_lds16((char*)sm[2 + buf] + wv * 2048,        Btc + ((size_t)(n0 + r0) * K + t * 32) * 2 + c0);
      gl_lds16((char*)sm[2 + buf] + wv * 2048 + 1024, Btc + ((size_t)(n0 + r1) * K + t * 32) * 2 + c1);
    };
    stage(0, 0);
    __syncthreads();
    for (int t = 0; t < nk; ++t) {
      const int cur = t & 1;
      if (t + 1 < nk) stage(cur ^ 1, t + 1);
      const char* AsB = (const char*)sm[cur];
      const char* BsB = (const char*)sm[2 + cur];
      bf16x8 af[4], bfr[4];
#pragma unroll
      for (int i = 0; i < 4; ++i)
        af[i] = *(const bf16x8*)(AsB + (wr + i * 16 + lr) * 64 + lk * 16);
#pragma unroll
      for (int j = 0; j < 4; ++j)
        bfr[j] = *(const bf16x8*)(BsB + (wc + j * 16 + lr) * 64 + lk * 16);
#pragma unroll
      for (int i = 0; i < 4; ++i)
#pragma unroll
        for (int j = 0; j < 4; ++j)
          acc[i][j] = __builtin_amdgcn_mfma_f32_16x16x32_bf16(af[i], bfr[j], acc[i][j], 0, 0, 0);
      __syncthreads();
    }
  }
#pragma unroll
  for (int i = 0; i < 4; ++i)
#pragma unroll
    for (int j = 0; j < 4; ++j) {
      float bv = bias[n0 + wc + j * 16 + lr];
#pragma unroll
      for (int r = 0; r < 4; ++r)
        Y[(size_t)(m0 + wr + i * 16 + lk * 4 + r) * N + n0 + wc + j * 16 + lr] =
            acc[i][j][r] + bv;
    }
}

// ---------------------------------------------------------------- attention
// out = (Vsum - softmax(QK^T/8) V)/1023.  Q pre-scaled by 0.125*log2e; p=2^s.
// Swapped QK^T with σ-permuted K rows (σ(i): rotate bits 4..2) makes the
// in-register P fragments land EXACTLY in the mfma_16x16x32 A-layout:
//   pa_c[j] = P[q=lr][kv = c*32 + lk*8 + j]   (j=0..3←sacc[2c], j=4..7←sacc[2c+1])
// → PV and rowsum run on x32 MFMAs (full rate) with V as b128 fragments.
__global__ __launch_bounds__(256) void k_attn(
    const bf16_t* __restrict__ Qp, const bf16_t* __restrict__ Kp,
    const bf16_t* __restrict__ Vt, const float* __restrict__ Vsum,
    bf16_t* __restrict__ Aout) {
  const int bid = blockIdx.x;
  const int wgid = (bid & 7) * 128 + (bid >> 3);   // XCD-grouping, 1024 blocks
  const int qg = wgid & 7;
  const int bh = wgid >> 3;
  const int b = bh >> 4, h = bh & 15;
  __shared__ bf16_t Ks[2][64 * 64];
  __shared__ bf16_t Vs[2][64 * 64];
  const int lane = threadIdx.x & 63;
  const int wv = threadIdx.x >> 6;
  const int lr = lane & 15, lk = lane >> 4;

  const int o0 = wv * 2048 + lane * 16;
  const int o1 = o0 + 1024;
  const int row0 = o0 >> 7, row1 = o1 >> 7;
  const int sc0 = ((((o0 >> 4) & 7) ^ (row0 & 7)) << 4);
  const int sc1 = ((((o1 >> 4) & 7) ^ (row1 & 7)) << 4);
  // σ: LDS row i holds K row σ(i) (rotate bits 4..2 left)
  const int srow0 = (row0 & 0x23) | ((row0 & 0x0C) << 1) | ((row0 & 0x10) >> 2);
  const int srow1 = (row1 & 0x23) | ((row1 & 0x0C) << 1) | ((row1 & 0x10) >> 2);

  const char* Ksrc0 = (const char*)(Kp + ((size_t)(b * 1024 + srow0)) * 1024 + h * 64) + sc0;
  const char* Ksrc1 = (const char*)(Kp + ((size_t)(b * 1024 + srow1)) * 1024 + h * 64) + sc1;
  const char* Vtile = (const char*)Vt + (size_t)bh * 131072 + o0;

  gl_lds16((char*)&Ks[0][0] + o0, Ksrc0);
  gl_lds16((char*)&Ks[0][0] + o1, Ksrc1);
  gl_lds16((char*)&Vs[0][0] + o0, Vtile);
  gl_lds16((char*)&Vs[0][0] + o1, Vtile + 1024);

  bf16x8 qa[2][2];
#pragma unroll
  for (int st = 0; st < 2; ++st) {
    const char* qsrc =
        (const char*)(Qp + ((size_t)(b * 1024 + qg * 128 + st * 64 + wv * 16 + lr)) * 1024 + h * 64);
    qa[st][0] = *(const bf16x8*)(qsrc + lk * 16);
    qa[st][1] = *(const bf16x8*)(qsrc + 64 + lk * 16);
  }
  __syncthreads();

  const int kb0 = lr * 128 + ((lk ^ (lr & 7)) << 4);
  const int kb1 = lr * 128 + (((4 + lk) ^ (lr & 7)) << 4);
  // V b128 fragment: chunk c covers kv c*32+lk*8..+7 → 16B chunk idx c*4+lk
  const int vsw0 = lr * 128 + (((0 + lk) ^ (lr & 7)) << 4);
  const int vsw1 = lr * 128 + (((4 + lk) ^ (lr & 7)) << 4);

  f32x4 zro = {0.f, 0.f, 0.f, 0.f};
  f32x4 oacc[2][4];
  f32x4 sum[2];
#pragma unroll
  for (int st = 0; st < 2; ++st) {
    sum[st] = zro;
#pragma unroll
    for (int g = 0; g < 4; ++g) oacc[st][g] = zro;
  }
  bf16x8 ones8;
#pragma unroll
  for (int j = 0; j < 8; ++j) ones8[j] = (bf16_t)1.0f;

  for (int kt = 0; kt < 16; ++kt) {
    const int cur = kt & 1;
    const char* KsB = (const char*)&Ks[cur][0];
    const char* VsB = (const char*)&Vs[cur][0];
    if (kt < 15) {
      char* KsN = (char*)&Ks[cur ^ 1][0];
      char* VsN = (char*)&Vs[cur ^ 1][0];
      const size_t koff = (size_t)(kt + 1) * 131072;
      const size_t voff = (size_t)(kt + 1) * 8192;
      gl_lds16(KsN + o0, Ksrc0 + koff);
      gl_lds16(KsN + o1, Ksrc1 + koff);
      gl_lds16(VsN + o0, Vtile + voff);
      gl_lds16(VsN + o1, Vtile + voff + 1024);
    }

    // S^T = K Q^T (σ-permuted rows) for both subtiles; K frags shared
    f32x4 sacc[2][4];
#pragma unroll
    for (int st = 0; st < 2; ++st)
#pragma unroll
      for (int g = 0; g < 4; ++g) sacc[st][g] = zro;
    {
      bf16x8 kf[4];
#pragma unroll
      for (int g = 0; g < 4; ++g) kf[g] = *(const bf16x8*)(KsB + kb0 + g * 2048);
#pragma unroll
      for (int st = 0; st < 2; ++st)
#pragma unroll
        for (int g = 0; g < 4; ++g)
          sacc[st][g] = __builtin_amdgcn_mfma_f32_16x16x32_bf16(kf[g], qa[st][0], sacc[st][g], 0, 0, 0);
#pragma unroll
      for (int g = 0; g < 4; ++g) kf[g] = *(const bf16x8*)(KsB + kb1 + g * 2048);
#pragma unroll
      for (int st = 0; st < 2; ++st)
#pragma unroll
        for (int g = 0; g < 4; ++g)
          sacc[st][g] = __builtin_amdgcn_mfma_f32_16x16x32_bf16(kf[g], qa[st][1], sacc[st][g], 0, 0, 0);
    }

    // p = 2^s, packed directly into x32 A-fragments (j=0..3←g=2c, j=4..7←g=2c+1)
    bf16x8 pa[2][2];
#pragma unroll
    for (int st = 0; st < 2; ++st)
#pragma unroll
      for (int c = 0; c < 2; ++c) {
        bf16x8 pw;
#pragma unroll
        for (int r = 0; r < 4; ++r) {
          pw[r]     = (bf16_t)EXP2(sacc[st][2 * c][r]);
          pw[4 + r] = (bf16_t)EXP2(sacc[st][2 * c + 1][r]);
        }
        pa[st][c] = pw;
      }

    // O += P V (x32); rowsum += P·1 — V b128 fragments shared across subtiles
#pragma unroll
    for (int c = 0; c < 2; ++c) {
      const int vb = (c == 0) ? vsw0 : vsw1;
      bf16x8 vf[4];
#pragma unroll
      for (int gd = 0; gd < 4; ++gd)
        vf[gd] = *(const bf16x8*)(VsB + vb + gd * 2048);
#pragma unroll
      for (int st = 0; st < 2; ++st) {
        sum[st] = __builtin_amdgcn_mfma_f32_16x16x32_bf16(pa[st][c], ones8, sum[st], 0, 0, 0);
#pragma unroll
        for (int gd = 0; gd < 4; ++gd)
          oacc[st][gd] = __builtin_amdgcn_mfma_f32_16x16x32_bf16(pa[st][c], vf[gd], oacc[st][gd], 0, 0, 0);
      }
    }
    __syncthreads();
  }

  // epilogue — sums in oacc row layout, lane-local
  float vs_d[4];
#pragma unroll
  for (int gd = 0; gd < 4; ++gd) vs_d[gd] = Vsum[bh * 64 + gd * 16 + lr];
#pragma unroll
  for (int st = 0; st < 2; ++st) {
    float inv[4];
#pragma unroll
    for (int r = 0; r < 4; ++r) inv[r] = 1.0f / sum[st][r];
#pragma unroll
    for (int gd = 0; gd < 4; ++gd)
#pragma unroll
      for (int r = 0; r < 4; ++r) {
        int d = gd * 16 + lr;
        int qrow = qg * 128 + st * 64 + wv * 16 + lk * 4 + r;
        float attnv = oacc[st][gd][r] * inv[r];
        float val = (vs_d[gd] - attnv) * (1.0f / 1023.0f);
        Aout[((size_t)(b * 1024 + qrow)) * 1024 + h * 64 + d] = (bf16_t)val;
      }
  }
}

// ---------------------------------------------------------------- layernorm
__global__ __launch_bounds__(256) void k_ln(
    const float* __restrict__ Y, const float* __restrict__ gamma,
    const float* __restrict__ beta, float* __restrict__ out) {
  const int row = blockIdx.x, tid = threadIdx.x;
  const float4 x = reinterpret_cast<const float4*>(Y + (size_t)row * 1024)[tid];
  float s = x.x + x.y + x.z + x.w;
  float q = x.x * x.x + x.y * x.y + x.z * x.z + x.w * x.w;
#pragma unroll
  for (int off = 32; off > 0; off >>= 1) {
    s += __shfl_xor(s, off, 64);
    q += __shfl_xor(q, off, 64);
  }
  __shared__ float ss[4], qs[4];
  if ((tid & 63) == 0) { ss[tid >> 6] = s; qs[tid >> 6] = q; }
  __syncthreads();
  s = ss[0] + ss[1] + ss[2] + ss[3];
  q = qs[0] + qs[1] + qs[2] + qs[3];
  float mean = s * (1.f / 1024.f);
  float var = q * (1.f / 1024.f) - mean * mean;
  float rstd = rsqrtf(var + 1e-5f);
  float4 g = reinterpret_cast<const float4*>(gamma)[tid];
  float4 bt = reinterpret_cast<const float4*>(beta)[tid];
  float4 o;
  o.x = (x.x - mean) * rstd * g.x + bt.x;
  o.y = (x.y - mean) * rstd * g.y + bt.y;
  o.z = (x.z - mean) * rstd * g.z + bt.z;
  o.w = (x.w - mean) * rstd * g.w + bt.w;
  reinterpret_cast<float4*>(out + (size_t)row * 1024)[tid] = o;
}

// ---------------------------------------------------------------- launch
extern "C" void kernel_launch(void* const* d_in, const int* in_sizes, int n_in,
                              void* d_out, int out_size, void* d_ws, size_t ws_size,
                              hipStream_t stream) {
  (void)in_sizes; (void)n_in; (void)out_size;
  const float* q       = (const float*)d_in[0];
  const float* k       = (const float*)d_in[1];
  const float* v       = (const float*)d_in[2];
  const float* w_qs    = (const float*)d_in[3];
  const float* w_ks    = (const float*)d_in[4];
  const float* w_vs    = (const float*)d_in[5];
  const float* fc_w    = (const float*)d_in[6];
  const float* resid_w = (const float*)d_in[7];
  const float* resid_b = (const float*)d_in[8];
  const float* ln_g    = (const float*)d_in[9];
  const float* ln_b    = (const float*)d_in[10];
  float* out = (float*)d_out;
  char* ws = (char*)d_ws;

  if (ws_size < (size_t)122716160) return;  // need ~117 MB

  bf16_t* qb   = (bf16_t*)(ws + 0);
  bf16_t* kb   = (bf16_t*)(ws + 12582912);
  bf16_t* vb   = (bf16_t*)(ws + 29360128);
  float*  Y    = (float*)(ws + 12582912);   // aliases kb+vb (dead after projections)
  bf16_t* wqsT = (bf16_t*)(ws + 46137344);
  bf16_t* wksT = (bf16_t*)(ws + 47710208);
  bf16_t* wvsT = (bf16_t*)(ws + 49807360);
  bf16_t* fcwT = (bf16_t*)(ws + 51904512);
  bf16_t* rswT = (bf16_t*)(ws + 54001664);
  bf16_t* Qp   = (bf16_t*)(ws + 55574528);
  bf16_t* Kp   = (bf16_t*)(ws + 72351744);
  bf16_t* Vp   = (bf16_t*)(ws + 89128960);
  bf16_t* Aout = (bf16_t*)(ws + 89128960);  // aliases Vp (dead after transpose_v)
  bf16_t* VtT  = (bf16_t*)(ws + 105906176);
  float*  Vsm  = (float*)(ws + 122683392);

  k_convert_all<<<2048, 256, 0, stream>>>(q, k, v, qb, kb, vb, Vsm);
  k_transpose_all<<<1152, 256, 0, stream>>>(w_qs, w_ks, w_vs, fc_w, resid_w,
                                            wqsT, wksT, wvsT, fcwT, rswT);
  // Q pre-scale: 1/8 * log2(e) so scores feed 2^x directly
  k_gemm_proj<<<1536, 256, 0, stream>>>(qb, wqsT, Qp, kb, wksT, Kp, vb, wvsT, Vp,
                                        0.18033688011f);
  k_transpose_v<<<2048, 256, 0, stream>>>(Vp, VtT, Vsm);
  k_attn<<<1024, 256, 0, stream>>>(Qp, Kp, VtT, Vsm, Aout);
  k_gemm_final<<<512, 256, 0, stream>>>(Aout, fcwT, 1024, qb, rswT, 768, resid_b, Y, 1024);
  k_ln<<<8192, 256, 0, stream>>>(Y, ln_g, ln_b, out);
}

// Round 8
// 195.428 us; speedup vs baseline: 1.2077x; 1.0149x over previous
//
#include <hip/hip_runtime.h>

typedef __bf16 bf16_t;
typedef __bf16 bf16x8 __attribute__((ext_vector_type(8)));
typedef __bf16 bf16x4 __attribute__((ext_vector_type(4)));
typedef float  f32x4  __attribute__((ext_vector_type(4)));

#if __has_builtin(__builtin_amdgcn_exp2f)
#define EXP2(x) __builtin_amdgcn_exp2f(x)
#else
#define EXP2(x) exp2f(x)
#endif

#define DEVFN __device__ __forceinline__

DEVFN void gl_lds16(void* lds_base, const void* gsrc) {
  __builtin_amdgcn_global_load_lds(
      (const __attribute__((address_space(1))) void*)gsrc,
      (__attribute__((address_space(3))) void*)lds_base, 16, 0, 0);
}

// ---------------------------------------------------------------- prep:
// weight transposes (bid<1152) + q/k/v f32->bf16 converts (+ Vsum zero)
__global__ __launch_bounds__(256) void k_prep(
    const float* __restrict__ q, const float* __restrict__ k, const float* __restrict__ v,
    const float* __restrict__ w_qs, const float* __restrict__ w_ks,
    const float* __restrict__ w_vs, const float* __restrict__ fc_w,
    const float* __restrict__ resid_w,
    bf16_t* __restrict__ qb, bf16_t* __restrict__ kb, bf16_t* __restrict__ vb,
    bf16_t* __restrict__ wqsT, bf16_t* __restrict__ wksT, bf16_t* __restrict__ wvsT,
    bf16_t* __restrict__ fcwT, bf16_t* __restrict__ rswT,
    float* __restrict__ Vs) {
  __shared__ float t[64][65];
  int bid = blockIdx.x;
  if (bid < 1152) {
    const float* w; bf16_t* wt; int K;
    if (bid < 192)      { w = w_qs;    wt = wqsT; K = 768; }
    else if (bid < 448) { w = w_ks;    wt = wksT; K = 1024; bid -= 192; }
    else if (bid < 704) { w = w_vs;    wt = wvsT; K = 1024; bid -= 448; }
    else if (bid < 960) { w = fc_w;    wt = fcwT; K = 1024; bid -= 704; }
    else                { w = resid_w; wt = rswT; K = 768;  bid -= 960; }
    const int bk = (bid >> 4) << 6;
    const int bn = (bid & 15) << 6;
    const int rr = threadIdx.x >> 4;
    const int cc = (threadIdx.x & 15) << 2;
#pragma unroll
    for (int i = 0; i < 4; ++i) {
      int r = i * 16 + rr;
      float4 vv = *reinterpret_cast<const float4*>(&w[(size_t)(bk + r) * 1024 + bn + cc]);
      t[r][cc] = vv.x; t[r][cc + 1] = vv.y; t[r][cc + 2] = vv.z; t[r][cc + 3] = vv.w;
    }
    __syncthreads();
#pragma unroll
    for (int i = 0; i < 4; ++i) {
      int n = i * 16 + rr;
      bf16x4 o;
      o[0] = (bf16_t)t[cc][n];     o[1] = (bf16_t)t[cc + 1][n];
      o[2] = (bf16_t)t[cc + 2][n]; o[3] = (bf16_t)t[cc + 3][n];
      *reinterpret_cast<bf16x4*>(&wt[(size_t)(bn + n) * K + bk + cc]) = o;
    }
    return;
  }
  bid -= 1152;
  if (bid == 0) {
    for (int j = threadIdx.x; j < 8192; j += 256) Vs[j] = 0.f;  // atomic target
  }
  const int NQ = 1572864, NK = 2097152, NT = NQ + 2 * NK;
  int stride = (gridDim.x - 1152) * 256;
  for (int i = bid * 256 + threadIdx.x; i < NT; i += stride) {
    const float* src; bf16_t* dst; int off;
    if (i < NQ)           { src = q; dst = qb; off = i; }
    else if (i < NQ + NK) { src = k; dst = kb; off = i - NQ; }
    else                  { src = v; dst = vb; off = i - NQ - NK; }
    float4 vv = reinterpret_cast<const float4*>(src)[off];
    bf16x4 o;
    o[0] = (bf16_t)vv.x; o[1] = (bf16_t)vv.y; o[2] = (bf16_t)vv.z; o[3] = (bf16_t)vv.w;
    reinterpret_cast<bf16x4*>(dst)[off] = o;
  }
}

// ---------------------------------------------------------------- V transpose + column sums
__global__ __launch_bounds__(256) void k_transpose_v(
    const bf16_t* __restrict__ Vp, bf16_t* __restrict__ Vt, float* __restrict__ Vs) {
  const int kt = blockIdx.x & 15;
  const int bh = blockIdx.x >> 4;
  const int b = bh >> 4, h = bh & 15;
  __shared__ unsigned short t[64][72];
  __shared__ float red[4][64];
#pragma unroll
  for (int i = 0; i < 2; ++i) {
    int cid = i * 256 + threadIdx.x;
    int r = cid >> 3, c = (cid & 7) * 8;
    uint4 v = *reinterpret_cast<const uint4*>(
        Vp + ((size_t)(b * 1024 + kt * 64 + r)) * 1024 + h * 64 + c);
    const unsigned short* pv = reinterpret_cast<const unsigned short*>(&v);
#pragma unroll
    for (int j = 0; j < 8; ++j) t[r][c + j] = pv[j];
  }
  __syncthreads();
#pragma unroll
  for (int i = 0; i < 2; ++i) {
    int cid = i * 256 + threadIdx.x;
    int d = cid >> 3, c = (cid & 7) * 8;
    unsigned short tmp[8];
#pragma unroll
    for (int j = 0; j < 8; ++j) tmp[j] = t[c + j][d];
    char* dst = (char*)Vt + ((size_t)(bh * 16 + kt)) * 8192 + d * 128 +
                ((((c >> 3) ^ (d & 7))) << 4);
    *reinterpret_cast<uint4*>(dst) = *reinterpret_cast<uint4*>(tmp);
  }
  const int d = threadIdx.x & 63, seg = threadIdx.x >> 6;
  float s = 0.f;
#pragma unroll
  for (int i = 0; i < 16; ++i)
    s += (float)*(const bf16_t*)&t[seg * 16 + i][d];
  red[seg][d] = s;
  __syncthreads();
  if (threadIdx.x < 64)
    atomicAdd(&Vs[bh * 64 + threadIdx.x],
              red[0][threadIdx.x] + red[1][threadIdx.x] + red[2][threadIdx.x] + red[3][threadIdx.x]);
}

// ---------------------------------------------------------------- GEMM core (double-buffered,
// LDS chunk-swizzle: chunk c of 64B-row r stored at c^(r&3) → 4-way not 8-way conflicts)
DEVFN void gemm_core(const bf16_t* __restrict__ A, const bf16_t* __restrict__ Bt,
                     bf16_t* __restrict__ C, int N, int K, float oscale,
                     int wg, bf16_t (*sm)[4096]) {
  const int tn = N >> 7;
  const int m0 = (wg / tn) << 7;
  const int n0 = (wg % tn) << 7;
  const int lane = threadIdx.x & 63;
  const int wv = threadIdx.x >> 6;
  const int wr = (wv >> 1) * 64, wc = (wv & 1) * 64;
  const int lr = lane & 15, lk = lane >> 4;
  const int so0 = wv * 2048 + lane * 16;
  const int so1 = so0 + 1024;
  const int r0 = so0 >> 6, r1 = so1 >> 6;
  const int c0 = ((((so0 >> 4) & 3) ^ (r0 & 3)) << 4);   // swizzled source chunk
  const int c1 = ((((so1 >> 4) & 3) ^ (r1 & 3)) << 4);
  const int asw = ((lk ^ (lr & 3)) << 4);                // swizzled read chunk
  const char* Apc = (const char*)A;
  const char* Btc = (const char*)Bt;
  f32x4 zro = {0.f, 0.f, 0.f, 0.f};
  f32x4 acc[4][4];
#pragma unroll
  for (int i = 0; i < 4; ++i)
#pragma unroll
    for (int j = 0; j < 4; ++j) acc[i][j] = zro;

  const int nk = K >> 5;
  auto stage = [&](int buf, int t) {
    gl_lds16((char*)sm[buf] + wv * 2048,        Apc + ((size_t)(m0 + r0) * K + t * 32) * 2 + c0);
    gl_lds16((char*)sm[buf] + wv * 2048 + 1024, Apc + ((size_t)(m0 + r1) * K + t * 32) * 2 + c1);
    gl_lds16((char*)sm[2 + buf] + wv * 2048,        Btc + ((size_t)(n0 + r0) * K + t * 32) * 2 + c0);
    gl_lds16((char*)sm[2 + buf] + wv * 2048 + 1024, Btc + ((size_t)(n0 + r1) * K + t * 32) * 2 + c1);
  };
  stage(0, 0);
  __syncthreads();
  for (int t = 0; t < nk; ++t) {
    const int cur = t & 1;
    if (t + 1 < nk) stage(cur ^ 1, t + 1);
    const char* AsB = (const char*)sm[cur];
    const char* BsB = (const char*)sm[2 + cur];
    bf16x8 af[4], bfr[4];
#pragma unroll
    for (int i = 0; i < 4; ++i)
      af[i] = *(const bf16x8*)(AsB + (wr + i * 16 + lr) * 64 + asw);
#pragma unroll
    for (int j = 0; j < 4; ++j)
      bfr[j] = *(const bf16x8*)(BsB + (wc + j * 16 + lr) * 64 + asw);
#pragma unroll
    for (int i = 0; i < 4; ++i)
#pragma unroll
      for (int j = 0; j < 4; ++j)
        acc[i][j] = __builtin_amdgcn_mfma_f32_16x16x32_bf16(af[i], bfr[j], acc[i][j], 0, 0, 0);
    __syncthreads();
  }
#pragma unroll
  for (int i = 0; i < 4; ++i)
#pragma unroll
    for (int j = 0; j < 4; ++j)
#pragma unroll
      for (int r = 0; r < 4; ++r)
        C[(size_t)(m0 + wr + i * 16 + lk * 4 + r) * N + n0 + wc + j * 16 + lr] =
            (bf16_t)(acc[i][j][r] * oscale);
}

// fused Q/K/V projections: 1536 blocks, 512 per projection
__global__ __launch_bounds__(256) void k_gemm_proj(
    const bf16_t* __restrict__ qb, const bf16_t* __restrict__ wqsT, bf16_t* __restrict__ Qp,
    const bf16_t* __restrict__ kb, const bf16_t* __restrict__ wksT, bf16_t* __restrict__ Kp,
    const bf16_t* __restrict__ vb, const bf16_t* __restrict__ wvsT, bf16_t* __restrict__ Vp,
    float qscale) {
  __shared__ bf16_t sm[4][4096];
  const int bid = blockIdx.x;
  const int route = bid >> 9;
  const int sbid = bid & 511;
  const int wg = (sbid & 7) * 64 + (sbid >> 3);   // XCD-grouped
  if (route == 0)      gemm_core(qb, wqsT, Qp, 1024, 768,  qscale, wg, sm);
  else if (route == 1) gemm_core(kb, wksT, Kp, 1024, 1024, 1.0f,   wg, sm);
  else                 gemm_core(vb, wvsT, Vp, 1024, 1024, 1.0f,   wg, sm);
}

// Y[M,N] bf16 = A1*B1t^T + A2*B2t^T + bias  (double-buffered, swizzled LDS)
__global__ __launch_bounds__(256) void k_gemm_final(
    const bf16_t* __restrict__ A1, const bf16_t* __restrict__ B1t, int K1,
    const bf16_t* __restrict__ A2, const bf16_t* __restrict__ B2t, int K2,
    const float* __restrict__ bias, bf16_t* __restrict__ Y, int N) {
  __shared__ bf16_t sm[4][4096];
  const int bpx = gridDim.x >> 3;
  const int wg = (blockIdx.x & 7) * bpx + (blockIdx.x >> 3);
  const int tn = N >> 7;
  const int m0 = (wg / tn) << 7;
  const int n0 = (wg % tn) << 7;
  const int lane = threadIdx.x & 63;
  const int wv = threadIdx.x >> 6;
  const int wr = (wv >> 1) * 64, wc = (wv & 1) * 64;
  const int lr = lane & 15, lk = lane >> 4;
  const int so0 = wv * 2048 + lane * 16;
  const int so1 = so0 + 1024;
  const int r0 = so0 >> 6, r1 = so1 >> 6;
  const int c0 = ((((so0 >> 4) & 3) ^ (r0 & 3)) << 4);
  const int c1 = ((((so1 >> 4) & 3) ^ (r1 & 3)) << 4);
  const int asw = ((lk ^ (lr & 3)) << 4);
  f32x4 zro = {0.f, 0.f, 0.f, 0.f};
  f32x4 acc[4][4];
#pragma unroll
  for (int i = 0; i < 4; ++i)
#pragma unroll
    for (int j = 0; j < 4; ++j) acc[i][j] = zro;

  const bf16_t* Ap[2] = {A1, A2};
  const bf16_t* Bp[2] = {B1t, B2t};
  const int Kp_[2] = {K1, K2};
  for (int ph = 0; ph < 2; ++ph) {
    const char* Apc = (const char*)Ap[ph];
    const char* Btc = (const char*)Bp[ph];
    const int K = Kp_[ph];
    const int nk = K >> 5;
    auto stage = [&](int buf, int t) {
      gl_lds16((char*)sm[buf] + wv * 2048,        Apc + ((size_t)(m0 + r0) * K + t * 32) * 2 + c0);
      gl_lds16((char*)sm[buf] + wv * 2048 + 1024, Apc + ((size_t)(m0 + r1) * K + t * 32) * 2 + c1);
      gl_lds16((char*)sm[2 + buf] + wv * 2048,        Btc + ((size_t)(n0 + r0) * K + t * 32) * 2 + c0);
      gl_lds16((char*)sm[2 + buf] + wv * 2048 + 1024, Btc + ((size_t)(n0 + r1) * K + t * 32) * 2 + c1);
    };
    stage(0, 0);
    __syncthreads();
    for (int t = 0; t < nk; ++t) {
      const int cur = t & 1;
      if (t + 1 < nk) stage(cur ^ 1, t + 1);
      const char* AsB = (const char*)sm[cur];
      const char* BsB = (const char*)sm[2 + cur];
      bf16x8 af[4], bfr[4];
#pragma unroll
      for (int i = 0; i < 4; ++i)
        af[i] = *(const bf16x8*)(AsB + (wr + i * 16 + lr) * 64 + asw);
#pragma unroll
      for (int j = 0; j < 4; ++j)
        bfr[j] = *(const bf16x8*)(BsB + (wc + j * 16 + lr) * 64 + asw);
#pragma unroll
      for (int i = 0; i < 4; ++i)
#pragma unroll
        for (int j = 0; j < 4; ++j)
          acc[i][j] = __builtin_amdgcn_mfma_f32_16x16x32_bf16(af[i], bfr[j], acc[i][j], 0, 0, 0);
      __syncthreads();
    }
  }
#pragma unroll
  for (int i = 0; i < 4; ++i)
#pragma unroll
    for (int j = 0; j < 4; ++j) {
      float bv = bias[n0 + wc + j * 16 + lr];
#pragma unroll
      for (int r = 0; r < 4; ++r)
        Y[(size_t)(m0 + wr + i * 16 + lk * 4 + r) * N + n0 + wc + j * 16 + lr] =
            (bf16_t)(acc[i][j][r] + bv);
    }
}

// ---------------------------------------------------------------- attention (unchanged from r7)
__global__ __launch_bounds__(256) void k_attn(
    const bf16_t* __restrict__ Qp, const bf16_t* __restrict__ Kp,
    const bf16_t* __restrict__ Vt, const float* __restrict__ Vsum,
    bf16_t* __restrict__ Aout) {
  const int bid = blockIdx.x;
  const int wgid = (bid & 7) * 128 + (bid >> 3);   // XCD-grouping, 1024 blocks
  const int qg = wgid & 7;
  const int bh = wgid >> 3;
  const int b = bh >> 4, h = bh & 15;
  __shared__ bf16_t Ks[2][64 * 64];
  __shared__ bf16_t Vs[2][64 * 64];
  const int lane = threadIdx.x & 63;
  const int wv = threadIdx.x >> 6;
  const int lr = lane & 15, lk = lane >> 4;

  const int o0 = wv * 2048 + lane * 16;
  const int o1 = o0 + 1024;
  const int row0 = o0 >> 7, row1 = o1 >> 7;
  const int sc0 = ((((o0 >> 4) & 7) ^ (row0 & 7)) << 4);
  const int sc1 = ((((o1 >> 4) & 7) ^ (row1 & 7)) << 4);
  const int srow0 = (row0 & 0x23) | ((row0 & 0x0C) << 1) | ((row0 & 0x10) >> 2);
  const int srow1 = (row1 & 0x23) | ((row1 & 0x0C) << 1) | ((row1 & 0x10) >> 2);

  const char* Ksrc0 = (const char*)(Kp + ((size_t)(b * 1024 + srow0)) * 1024 + h * 64) + sc0;
  const char* Ksrc1 = (const char*)(Kp + ((size_t)(b * 1024 + srow1)) * 1024 + h * 64) + sc1;
  const char* Vtile = (const char*)Vt + (size_t)bh * 131072 + o0;

  gl_lds16((char*)&Ks[0][0] + o0, Ksrc0);
  gl_lds16((char*)&Ks[0][0] + o1, Ksrc1);
  gl_lds16((char*)&Vs[0][0] + o0, Vtile);
  gl_lds16((char*)&Vs[0][0] + o1, Vtile + 1024);

  bf16x8 qa[2][2];
#pragma unroll
  for (int st = 0; st < 2; ++st) {
    const char* qsrc =
        (const char*)(Qp + ((size_t)(b * 1024 + qg * 128 + st * 64 + wv * 16 + lr)) * 1024 + h * 64);
    qa[st][0] = *(const bf16x8*)(qsrc + lk * 16);
    qa[st][1] = *(const bf16x8*)(qsrc + 64 + lk * 16);
  }
  __syncthreads();

  const int kb0 = lr * 128 + ((lk ^ (lr & 7)) << 4);
  const int kb1 = lr * 128 + (((4 + lk) ^ (lr & 7)) << 4);
  const int vsw0 = lr * 128 + (((0 + lk) ^ (lr & 7)) << 4);
  const int vsw1 = lr * 128 + (((4 + lk) ^ (lr & 7)) << 4);

  f32x4 zro = {0.f, 0.f, 0.f, 0.f};
  f32x4 oacc[2][4];
  f32x4 sum[2];
#pragma unroll
  for (int st = 0; st < 2; ++st) {
    sum[st] = zro;
#pragma unroll
    for (int g = 0; g < 4; ++g) oacc[st][g] = zro;
  }
  bf16x8 ones8;
#pragma unroll
  for (int j = 0; j < 8; ++j) ones8[j] = (bf16_t)1.0f;

  for (int kt = 0; kt < 16; ++kt) {
    const int cur = kt & 1;
    const char* KsB = (const char*)&Ks[cur][0];
    const char* VsB = (const char*)&Vs[cur][0];
    if (kt < 15) {
      char* KsN = (char*)&Ks[cur ^ 1][0];
      char* VsN = (char*)&Vs[cur ^ 1][0];
      const size_t koff = (size_t)(kt + 1) * 131072;
      const size_t voff = (size_t)(kt + 1) * 8192;
      gl_lds16(KsN + o0, Ksrc0 + koff);
      gl_lds16(KsN + o1, Ksrc1 + koff);
      gl_lds16(VsN + o0, Vtile + voff);
      gl_lds16(VsN + o1, Vtile + voff + 1024);
    }

    f32x4 sacc[2][4];
#pragma unroll
    for (int st = 0; st < 2; ++st)
#pragma unroll
      for (int g = 0; g < 4; ++g) sacc[st][g] = zro;
    {
      bf16x8 kf[4];
#pragma unroll
      for (int g = 0; g < 4; ++g) kf[g] = *(const bf16x8*)(KsB + kb0 + g * 2048);
#pragma unroll
      for (int st = 0; st < 2; ++st)
#pragma unroll
        for (int g = 0; g < 4; ++g)
          sacc[st][g] = __builtin_amdgcn_mfma_f32_16x16x32_bf16(kf[g], qa[st][0], sacc[st][g], 0, 0, 0);
#pragma unroll
      for (int g = 0; g < 4; ++g) kf[g] = *(const bf16x8*)(KsB + kb1 + g * 2048);
#pragma unroll
      for (int st = 0; st < 2; ++st)
#pragma unroll
        for (int g = 0; g < 4; ++g)
          sacc[st][g] = __builtin_amdgcn_mfma_f32_16x16x32_bf16(kf[g], qa[st][1], sacc[st][g], 0, 0, 0);
    }

    bf16x8 pa[2][2];
#pragma unroll
    for (int st = 0; st < 2; ++st)
#pragma unroll
      for (int c = 0; c < 2; ++c) {
        bf16x8 pw;
#pragma unroll
        for (int r = 0; r < 4; ++r) {
          pw[r]     = (bf16_t)EXP2(sacc[st][2 * c][r]);
          pw[4 + r] = (bf16_t)EXP2(sacc[st][2 * c + 1][r]);
        }
        pa[st][c] = pw;
      }

#pragma unroll
    for (int c = 0; c < 2; ++c) {
      const int vb = (c == 0) ? vsw0 : vsw1;
      bf16x8 vf[4];
#pragma unroll
      for (int gd = 0; gd < 4; ++gd)
        vf[gd] = *(const bf16x8*)(VsB + vb + gd * 2048);
#pragma unroll
      for (int st = 0; st < 2; ++st) {
        sum[st] = __builtin_amdgcn_mfma_f32_16x16x32_bf16(pa[st][c], ones8, sum[st], 0, 0, 0);
#pragma unroll
        for (int gd = 0; gd < 4; ++gd)
          oacc[st][gd] = __builtin_amdgcn_mfma_f32_16x16x32_bf16(pa[st][c], vf[gd], oacc[st][gd], 0, 0, 0);
      }
    }
    __syncthreads();
  }

  float vs_d[4];
#pragma unroll
  for (int gd = 0; gd < 4; ++gd) vs_d[gd] = Vsum[bh * 64 + gd * 16 + lr];
#pragma unroll
  for (int st = 0; st < 2; ++st) {
    float inv[4];
#pragma unroll
    for (int r = 0; r < 4; ++r) inv[r] = 1.0f / sum[st][r];
#pragma unroll
    for (int gd = 0; gd < 4; ++gd)
#pragma unroll
      for (int r = 0; r < 4; ++r) {
        int d = gd * 16 + lr;
        int qrow = qg * 128 + st * 64 + wv * 16 + lk * 4 + r;
        float attnv = oacc[st][gd][r] * inv[r];
        float val = (vs_d[gd] - attnv) * (1.0f / 1023.0f);
        Aout[((size_t)(b * 1024 + qrow)) * 1024 + h * 64 + d] = (bf16_t)val;
      }
  }
}

// ---------------------------------------------------------------- layernorm (bf16 input)
__global__ __launch_bounds__(256) void k_ln(
    const bf16_t* __restrict__ Y, const float* __restrict__ gamma,
    const float* __restrict__ beta, float* __restrict__ out) {
  const int row = blockIdx.x, tid = threadIdx.x;
  bf16x4 xv = reinterpret_cast<const bf16x4*>(Y + (size_t)row * 1024)[tid];
  float x0 = (float)xv[0], x1 = (float)xv[1], x2 = (float)xv[2], x3 = (float)xv[3];
  float s = x0 + x1 + x2 + x3;
  float q = x0 * x0 + x1 * x1 + x2 * x2 + x3 * x3;
#pragma unroll
  for (int off = 32; off > 0; off >>= 1) {
    s += __shfl_xor(s, off, 64);
    q += __shfl_xor(q, off, 64);
  }
  __shared__ float ss[4], qs[4];
  if ((tid & 63) == 0) { ss[tid >> 6] = s; qs[tid >> 6] = q; }
  __syncthreads();
  s = ss[0] + ss[1] + ss[2] + ss[3];
  q = qs[0] + qs[1] + qs[2] + qs[3];
  float mean = s * (1.f / 1024.f);
  float var = q * (1.f / 1024.f) - mean * mean;
  float rstd = rsqrtf(var + 1e-5f);
  float4 g = reinterpret_cast<const float4*>(gamma)[tid];
  float4 bt = reinterpret_cast<const float4*>(beta)[tid];
  float4 o;
  o.x = (x0 - mean) * rstd * g.x + bt.x;
  o.y = (x1 - mean) * rstd * g.y + bt.y;
  o.z = (x2 - mean) * rstd * g.z + bt.z;
  o.w = (x3 - mean) * rstd * g.w + bt.w;
  reinterpret_cast<float4*>(out + (size_t)row * 1024)[tid] = o;
}

// ---------------------------------------------------------------- launch
extern "C" void kernel_launch(void* const* d_in, const int* in_sizes, int n_in,
                              void* d_out, int out_size, void* d_ws, size_t ws_size,
                              hipStream_t stream) {
  (void)in_sizes; (void)n_in; (void)out_size;
  const float* q       = (const float*)d_in[0];
  const float* k       = (const float*)d_in[1];
  const float* v       = (const float*)d_in[2];
  const float* w_qs    = (const float*)d_in[3];
  const float* w_ks    = (const float*)d_in[4];
  const float* w_vs    = (const float*)d_in[5];
  const float* fc_w    = (const float*)d_in[6];
  const float* resid_w = (const float*)d_in[7];
  const float* resid_b = (const float*)d_in[8];
  const float* ln_g    = (const float*)d_in[9];
  const float* ln_b    = (const float*)d_in[10];
  float* out = (float*)d_out;
  char* ws = (char*)d_ws;

  if (ws_size < (size_t)122716160) return;  // need ~117 MB

  bf16_t* qb   = (bf16_t*)(ws + 0);
  bf16_t* kb   = (bf16_t*)(ws + 12582912);
  bf16_t* vb   = (bf16_t*)(ws + 29360128);
  bf16_t* Y    = (bf16_t*)(ws + 12582912);  // aliases kb+vb (dead after projections)
  bf16_t* wqsT = (bf16_t*)(ws + 46137344);
  bf16_t* wksT = (bf16_t*)(ws + 47710208);
  bf16_t* wvsT = (bf16_t*)(ws + 49807360);
  bf16_t* fcwT = (bf16_t*)(ws + 51904512);
  bf16_t* rswT = (bf16_t*)(ws + 54001664);
  bf16_t* Qp   = (bf16_t*)(ws + 55574528);
  bf16_t* Kp   = (bf16_t*)(ws + 72351744);
  bf16_t* Vp   = (bf16_t*)(ws + 89128960);
  bf16_t* Aout = (bf16_t*)(ws + 89128960);  // aliases Vp (dead after transpose_v)
  bf16_t* VtT  = (bf16_t*)(ws + 105906176);
  float*  Vsm  = (float*)(ws + 122683392);

  k_prep<<<3200, 256, 0, stream>>>(q, k, v, w_qs, w_ks, w_vs, fc_w, resid_w,
                                   qb, kb, vb, wqsT, wksT, wvsT, fcwT, rswT, Vsm);
  // Q pre-scale: 1/8 * log2(e) so scores feed 2^x directly
  k_gemm_proj<<<1536, 256, 0, stream>>>(qb, wqsT, Qp, kb, wksT, Kp, vb, wvsT, Vp,
                                        0.18033688011f);
  k_transpose_v<<<2048, 256, 0, stream>>>(Vp, VtT, Vsm);
  k_attn<<<1024, 256, 0, stream>>>(Qp, Kp, VtT, Vsm, Aout);
  k_gemm_final<<<512, 256, 0, stream>>>(Aout, fcwT, 1024, qb, rswT, 768, resid_b, Y, 1024);
  k_ln<<<8192, 256, 0, stream>>>(Y, ln_g, ln_b, out);
}

// Round 9
// 178.806 us; speedup vs baseline: 1.3200x; 1.0930x over previous
//
#include <hip/hip_runtime.h>

typedef __bf16 bf16_t;
typedef __bf16 bf16x8 __attribute__((ext_vector_type(8)));
typedef __bf16 bf16x4 __attribute__((ext_vector_type(4)));
typedef float  f32x4  __attribute__((ext_vector_type(4)));

#if __has_builtin(__builtin_amdgcn_exp2f)
#define EXP2(x) __builtin_amdgcn_exp2f(x)
#else
#define EXP2(x) exp2f(x)
#endif

#define DEVFN __device__ __forceinline__

DEVFN void gl_lds16(void* lds_base, const void* gsrc) {
  __builtin_amdgcn_global_load_lds(
      (const __attribute__((address_space(1))) void*)gsrc,
      (__attribute__((address_space(3))) void*)lds_base, 16, 0, 0);
}

// ---------------------------------------------------------------- prep:
// weight transposes (bid<1152) + q/k/v f32->bf16 converts (+ Vsum zero)
__global__ __launch_bounds__(256) void k_prep(
    const float* __restrict__ q, const float* __restrict__ k, const float* __restrict__ v,
    const float* __restrict__ w_qs, const float* __restrict__ w_ks,
    const float* __restrict__ w_vs, const float* __restrict__ fc_w,
    const float* __restrict__ resid_w,
    bf16_t* __restrict__ qb, bf16_t* __restrict__ kb, bf16_t* __restrict__ vb,
    bf16_t* __restrict__ wqsT, bf16_t* __restrict__ wksT, bf16_t* __restrict__ wvsT,
    bf16_t* __restrict__ fcwT, bf16_t* __restrict__ rswT,
    float* __restrict__ Vs) {
  __shared__ float t[64][65];
  int bid = blockIdx.x;
  if (bid < 1152) {
    const float* w; bf16_t* wt; int K;
    if (bid < 192)      { w = w_qs;    wt = wqsT; K = 768; }
    else if (bid < 448) { w = w_ks;    wt = wksT; K = 1024; bid -= 192; }
    else if (bid < 704) { w = w_vs;    wt = wvsT; K = 1024; bid -= 448; }
    else if (bid < 960) { w = fc_w;    wt = fcwT; K = 1024; bid -= 704; }
    else                { w = resid_w; wt = rswT; K = 768;  bid -= 960; }
    const int bk = (bid >> 4) << 6;
    const int bn = (bid & 15) << 6;
    const int rr = threadIdx.x >> 4;
    const int cc = (threadIdx.x & 15) << 2;
#pragma unroll
    for (int i = 0; i < 4; ++i) {
      int r = i * 16 + rr;
      float4 vv = *reinterpret_cast<const float4*>(&w[(size_t)(bk + r) * 1024 + bn + cc]);
      t[r][cc] = vv.x; t[r][cc + 1] = vv.y; t[r][cc + 2] = vv.z; t[r][cc + 3] = vv.w;
    }
    __syncthreads();
#pragma unroll
    for (int i = 0; i < 4; ++i) {
      int n = i * 16 + rr;
      bf16x4 o;
      o[0] = (bf16_t)t[cc][n];     o[1] = (bf16_t)t[cc + 1][n];
      o[2] = (bf16_t)t[cc + 2][n]; o[3] = (bf16_t)t[cc + 3][n];
      *reinterpret_cast<bf16x4*>(&wt[(size_t)(bn + n) * K + bk + cc]) = o;
    }
    return;
  }
  bid -= 1152;
  if (bid == 0) {
    for (int j = threadIdx.x; j < 8192; j += 256) Vs[j] = 0.f;  // atomic target
  }
  const int NQ = 1572864, NK = 2097152, NT = NQ + 2 * NK;
  int stride = (gridDim.x - 1152) * 256;
  for (int i = bid * 256 + threadIdx.x; i < NT; i += stride) {
    const float* src; bf16_t* dst; int off;
    if (i < NQ)           { src = q; dst = qb; off = i; }
    else if (i < NQ + NK) { src = k; dst = kb; off = i - NQ; }
    else                  { src = v; dst = vb; off = i - NQ - NK; }
    float4 vv = reinterpret_cast<const float4*>(src)[off];
    bf16x4 o;
    o[0] = (bf16_t)vv.x; o[1] = (bf16_t)vv.y; o[2] = (bf16_t)vv.z; o[3] = (bf16_t)vv.w;
    reinterpret_cast<bf16x4*>(dst)[off] = o;
  }
}

// ---------------------------------------------------------------- GEMM tile compute (double-buffered)
DEVFN void gemm_tiles(const bf16_t* __restrict__ A, const bf16_t* __restrict__ Bt,
                      int K, int m0, int n0, bf16_t (*sm)[4096], f32x4 (&acc)[4][4]) {
  const int lane = threadIdx.x & 63;
  const int wv = threadIdx.x >> 6;
  const int wr = (wv >> 1) * 64, wc = (wv & 1) * 64;
  const int lr = lane & 15, lk = lane >> 4;
  const int so0 = wv * 2048 + lane * 16;
  const int so1 = so0 + 1024;
  const int r0 = so0 >> 6, r1 = so1 >> 6;
  const int c0 = ((((so0 >> 4) & 3) ^ (r0 & 3)) << 4);
  const int c1 = ((((so1 >> 4) & 3) ^ (r1 & 3)) << 4);
  const int asw = ((lk ^ (lr & 3)) << 4);
  const char* Apc = (const char*)A;
  const char* Btc = (const char*)Bt;
  f32x4 zro = {0.f, 0.f, 0.f, 0.f};
#pragma unroll
  for (int i = 0; i < 4; ++i)
#pragma unroll
    for (int j = 0; j < 4; ++j) acc[i][j] = zro;

  const int nk = K >> 5;
  auto stage = [&](int buf, int t) {
    gl_lds16((char*)sm[buf] + wv * 2048,        Apc + ((size_t)(m0 + r0) * K + t * 32) * 2 + c0);
    gl_lds16((char*)sm[buf] + wv * 2048 + 1024, Apc + ((size_t)(m0 + r1) * K + t * 32) * 2 + c1);
    gl_lds16((char*)sm[2 + buf] + wv * 2048,        Btc + ((size_t)(n0 + r0) * K + t * 32) * 2 + c0);
    gl_lds16((char*)sm[2 + buf] + wv * 2048 + 1024, Btc + ((size_t)(n0 + r1) * K + t * 32) * 2 + c1);
  };
  stage(0, 0);
  __syncthreads();
  for (int t = 0; t < nk; ++t) {
    const int cur = t & 1;
    if (t + 1 < nk) stage(cur ^ 1, t + 1);
    const char* AsB = (const char*)sm[cur];
    const char* BsB = (const char*)sm[2 + cur];
    bf16x8 af[4], bfr[4];
#pragma unroll
    for (int i = 0; i < 4; ++i)
      af[i] = *(const bf16x8*)(AsB + (wr + i * 16 + lr) * 64 + asw);
#pragma unroll
    for (int j = 0; j < 4; ++j)
      bfr[j] = *(const bf16x8*)(BsB + (wc + j * 16 + lr) * 64 + asw);
#pragma unroll
    for (int i = 0; i < 4; ++i)
#pragma unroll
      for (int j = 0; j < 4; ++j)
        acc[i][j] = __builtin_amdgcn_mfma_f32_16x16x32_bf16(af[i], bfr[j], acc[i][j], 0, 0, 0);
    __syncthreads();
  }
}

// fused Q/K/V projections: 1536 blocks, 512 per projection.
// V route writes DIRECTLY into the swizzled Vt tiled layout + Vsum atomics
// (replaces the old k_transpose_v pass).
__global__ __launch_bounds__(256) void k_gemm_proj(
    const bf16_t* __restrict__ qb, const bf16_t* __restrict__ wqsT, bf16_t* __restrict__ Qp,
    const bf16_t* __restrict__ kb, const bf16_t* __restrict__ wksT, bf16_t* __restrict__ Kp,
    const bf16_t* __restrict__ vb, const bf16_t* __restrict__ wvsT, bf16_t* __restrict__ Vt,
    float* __restrict__ Vsum, float qscale) {
  __shared__ bf16_t sm[4][4096];
  const int bid = blockIdx.x;
  const int route = bid >> 9;
  const int sbid = bid & 511;
  const int wg = (sbid & 7) * 64 + (sbid >> 3);   // XCD-grouped
  const int tn = 8;                                // N=1024 → 8 col tiles
  const int m0 = (wg / tn) << 7;
  const int n0 = (wg % tn) << 7;
  const int lane = threadIdx.x & 63;
  const int wv = threadIdx.x >> 6;
  const int wr = (wv >> 1) * 64, wc = (wv & 1) * 64;
  const int lr = lane & 15, lk = lane >> 4;
  f32x4 acc[4][4];

  if (route == 0) {
    gemm_tiles(qb, wqsT, 768, m0, n0, sm, acc);
#pragma unroll
    for (int i = 0; i < 4; ++i)
#pragma unroll
      for (int j = 0; j < 4; ++j)
#pragma unroll
        for (int r = 0; r < 4; ++r)
          Qp[(size_t)(m0 + wr + i * 16 + lk * 4 + r) * 1024 + n0 + wc + j * 16 + lr] =
              (bf16_t)(acc[i][j][r] * qscale);
  } else if (route == 1) {
    gemm_tiles(kb, wksT, 1024, m0, n0, sm, acc);
#pragma unroll
    for (int i = 0; i < 4; ++i)
#pragma unroll
      for (int j = 0; j < 4; ++j)
#pragma unroll
        for (int r = 0; r < 4; ++r)
          Kp[(size_t)(m0 + wr + i * 16 + lk * 4 + r) * 1024 + n0 + wc + j * 16 + lr] =
              (bf16_t)acc[i][j][r];
  } else {
    gemm_tiles(vb, wvsT, 1024, m0, n0, sm, acc);
    // fused transpose: rows m = kv, cols n = h*64+d → Vt[bh][kt] 8KB tiles
    const int b = m0 >> 10;
    const int h = (n0 + wc) >> 6;              // constant per wave
    const int kt = ((m0 & 1023) + wr) >> 6;    // constant per wave
    const size_t tbase = (size_t)(b * 16 + h) * 131072 + (size_t)kt * 8192;
#pragma unroll
    for (int i = 0; i < 4; ++i) {
      const int kvl = i * 16 + lk * 4;         // kv within tile (r adds 0..3)
      const int csel = kvl >> 3;               // 16B chunk index
      const int hoff = (kvl & 7) * 2;          // 8B half within chunk
#pragma unroll
      for (int j = 0; j < 4; ++j) {
        const int d = j * 16 + lr;
        bf16x4 pw;
#pragma unroll
        for (int r = 0; r < 4; ++r) pw[r] = (bf16_t)acc[i][j][r];
        char* dst = (char*)Vt + tbase + d * 128 + ((csel ^ (d & 7)) << 4) + hoff;
        *reinterpret_cast<bf16x4*>(dst) = pw;
      }
    }
    // column sums: reduce over i,r then across lk (lane bits 4,5), atomic per col
#pragma unroll
    for (int j = 0; j < 4; ++j) {
      float s = 0.f;
#pragma unroll
      for (int i = 0; i < 4; ++i)
#pragma unroll
        for (int r = 0; r < 4; ++r) s += acc[i][j][r];
      s += __shfl_xor(s, 16, 64);
      s += __shfl_xor(s, 32, 64);
      if (lane < 16)
        atomicAdd(&Vsum[(b * 16 + h) * 64 + j * 16 + lane], s);
    }
  }
}

// Y[M,N] bf16 = A1*B1t^T + A2*B2t^T + bias  (double-buffered, swizzled LDS)
__global__ __launch_bounds__(256) void k_gemm_final(
    const bf16_t* __restrict__ A1, const bf16_t* __restrict__ B1t, int K1,
    const bf16_t* __restrict__ A2, const bf16_t* __restrict__ B2t, int K2,
    const float* __restrict__ bias, bf16_t* __restrict__ Y, int N) {
  __shared__ bf16_t sm[4][4096];
  const int bpx = gridDim.x >> 3;
  const int wg = (blockIdx.x & 7) * bpx + (blockIdx.x >> 3);
  const int tn = N >> 7;
  const int m0 = (wg / tn) << 7;
  const int n0 = (wg % tn) << 7;
  const int lane = threadIdx.x & 63;
  const int wv = threadIdx.x >> 6;
  const int wr = (wv >> 1) * 64, wc = (wv & 1) * 64;
  const int lr = lane & 15, lk = lane >> 4;
  f32x4 acc[4][4];
  f32x4 acc2[4][4];
  gemm_tiles(A1, B1t, K1, m0, n0, sm, acc);
  __syncthreads();
  gemm_tiles(A2, B2t, K2, m0, n0, sm, acc2);
#pragma unroll
  for (int i = 0; i < 4; ++i)
#pragma unroll
    for (int j = 0; j < 4; ++j) {
      float bv = bias[n0 + wc + j * 16 + lr];
#pragma unroll
      for (int r = 0; r < 4; ++r)
        Y[(size_t)(m0 + wr + i * 16 + lk * 4 + r) * N + n0 + wc + j * 16 + lr] =
            (bf16_t)(acc[i][j][r] + acc2[i][j][r] + bv);
    }
}

// ---------------------------------------------------------------- attention
// QBLK=256, 512 threads (8 waves). Waves 0-3: subtiles 0,1; waves 4-7: 2,3.
// Each wave = r7 workload (2 subtiles share K/V fragments); one K/V staging
// serves 256 q-rows. σ-permuted K rows → in-register x32 P fragments.
__global__ __launch_bounds__(512) void k_attn(
    const bf16_t* __restrict__ Qp, const bf16_t* __restrict__ Kp,
    const bf16_t* __restrict__ Vt, const float* __restrict__ Vsum,
    bf16_t* __restrict__ Aout) {
  const int bid = blockIdx.x;
  const int wgid = (bid & 7) * 64 + (bid >> 3);   // XCD-grouping, 512 blocks
  const int qg = wgid & 3;                         // 256-row q-group
  const int bh = wgid >> 2;
  const int b = bh >> 4, h = bh & 15;
  __shared__ bf16_t Ks[2][4096];
  __shared__ bf16_t Vs[2][4096];
  const int tid = threadIdx.x;
  const int lane = tid & 63;
  const int wv = tid >> 6;
  const int lr = lane & 15, lk = lane >> 4;
  const int stb = (wv >> 2) * 2;     // subtile pair base: 0 or 2
  const int wrow = (wv & 3) * 16;    // row base within subtile

  const int o = tid * 16;            // 512*16 = 8KB: one load per tile
  const int row = o >> 7;
  const int sc = ((((o >> 4) & 7) ^ (row & 7)) << 4);
  const int srow = (row & 0x23) | ((row & 0x0C) << 1) | ((row & 0x10) >> 2);

  const char* Ksrc  = (const char*)(Kp + ((size_t)(b * 1024 + srow)) * 1024 + h * 64) + sc;
  const char* Vtile = (const char*)Vt + (size_t)bh * 131072 + o;

  gl_lds16((char*)&Ks[0][0] + o, Ksrc);
  gl_lds16((char*)&Vs[0][0] + o, Vtile);

  bf16x8 qa[2][2];
#pragma unroll
  for (int stl = 0; stl < 2; ++stl) {
    const char* qsrc = (const char*)(Qp +
        ((size_t)(b * 1024 + qg * 256 + (stb + stl) * 64 + wrow + lr)) * 1024 + h * 64);
    qa[stl][0] = *(const bf16x8*)(qsrc + lk * 16);
    qa[stl][1] = *(const bf16x8*)(qsrc + 64 + lk * 16);
  }
  __syncthreads();

  const int kb0 = lr * 128 + ((lk ^ (lr & 7)) << 4);
  const int kb1 = lr * 128 + (((4 + lk) ^ (lr & 7)) << 4);
  const int vsw0 = kb0;
  const int vsw1 = kb1;

  f32x4 zro = {0.f, 0.f, 0.f, 0.f};
  f32x4 oacc[2][4];
  f32x4 sum[2];
#pragma unroll
  for (int stl = 0; stl < 2; ++stl) {
    sum[stl] = zro;
#pragma unroll
    for (int g = 0; g < 4; ++g) oacc[stl][g] = zro;
  }
  bf16x8 ones8;
#pragma unroll
  for (int j = 0; j < 8; ++j) ones8[j] = (bf16_t)1.0f;

  for (int kt = 0; kt < 16; ++kt) {
    const int cur = kt & 1;
    const char* KsB = (const char*)&Ks[cur][0];
    const char* VsB = (const char*)&Vs[cur][0];
    if (kt < 15) {
      gl_lds16((char*)&Ks[cur ^ 1][0] + o, Ksrc + (size_t)(kt + 1) * 131072);
      gl_lds16((char*)&Vs[cur ^ 1][0] + o, Vtile + (size_t)(kt + 1) * 8192);
    }

    f32x4 sacc[2][4];
#pragma unroll
    for (int stl = 0; stl < 2; ++stl)
#pragma unroll
      for (int g = 0; g < 4; ++g) sacc[stl][g] = zro;
    {
      bf16x8 kf[4];
#pragma unroll
      for (int g = 0; g < 4; ++g) kf[g] = *(const bf16x8*)(KsB + kb0 + g * 2048);
#pragma unroll
      for (int stl = 0; stl < 2; ++stl)
#pragma unroll
        for (int g = 0; g < 4; ++g)
          sacc[stl][g] = __builtin_amdgcn_mfma_f32_16x16x32_bf16(kf[g], qa[stl][0], sacc[stl][g], 0, 0, 0);
#pragma unroll
      for (int g = 0; g < 4; ++g) kf[g] = *(const bf16x8*)(KsB + kb1 + g * 2048);
#pragma unroll
      for (int stl = 0; stl < 2; ++stl)
#pragma unroll
        for (int g = 0; g < 4; ++g)
          sacc[stl][g] = __builtin_amdgcn_mfma_f32_16x16x32_bf16(kf[g], qa[stl][1], sacc[stl][g], 0, 0, 0);
    }

    bf16x8 pa[2][2];
#pragma unroll
    for (int stl = 0; stl < 2; ++stl)
#pragma unroll
      for (int c = 0; c < 2; ++c) {
        bf16x8 pw;
#pragma unroll
        for (int r = 0; r < 4; ++r) {
          pw[r]     = (bf16_t)EXP2(sacc[stl][2 * c][r]);
          pw[4 + r] = (bf16_t)EXP2(sacc[stl][2 * c + 1][r]);
        }
        pa[stl][c] = pw;
      }

#pragma unroll
    for (int c = 0; c < 2; ++c) {
      const int vb = (c == 0) ? vsw0 : vsw1;
      bf16x8 vf[4];
#pragma unroll
      for (int gd = 0; gd < 4; ++gd)
        vf[gd] = *(const bf16x8*)(VsB + vb + gd * 2048);
#pragma unroll
      for (int stl = 0; stl < 2; ++stl) {
        sum[stl] = __builtin_amdgcn_mfma_f32_16x16x32_bf16(pa[stl][c], ones8, sum[stl], 0, 0, 0);
#pragma unroll
        for (int gd = 0; gd < 4; ++gd)
          oacc[stl][gd] = __builtin_amdgcn_mfma_f32_16x16x32_bf16(pa[stl][c], vf[gd], oacc[stl][gd], 0, 0, 0);
      }
    }
    __syncthreads();
  }

  float vs_d[4];
#pragma unroll
  for (int gd = 0; gd < 4; ++gd) vs_d[gd] = Vsum[bh * 64 + gd * 16 + lr];
#pragma unroll
  for (int stl = 0; stl < 2; ++stl) {
    float inv[4];
#pragma unroll
    for (int r = 0; r < 4; ++r) inv[r] = 1.0f / sum[stl][r];
#pragma unroll
    for (int gd = 0; gd < 4; ++gd)
#pragma unroll
      for (int r = 0; r < 4; ++r) {
        int d = gd * 16 + lr;
        int qrow = qg * 256 + (stb + stl) * 64 + wrow + lk * 4 + r;
        float attnv = oacc[stl][gd][r] * inv[r];
        float val = (vs_d[gd] - attnv) * (1.0f / 1023.0f);
        Aout[((size_t)(b * 1024 + qrow)) * 1024 + h * 64 + d] = (bf16_t)val;
      }
  }
}

// ---------------------------------------------------------------- layernorm (bf16 input)
__global__ __launch_bounds__(256) void k_ln(
    const bf16_t* __restrict__ Y, const float* __restrict__ gamma,
    const float* __restrict__ beta, float* __restrict__ out) {
  const int row = blockIdx.x, tid = threadIdx.x;
  bf16x4 xv = reinterpret_cast<const bf16x4*>(Y + (size_t)row * 1024)[tid];
  float x0 = (float)xv[0], x1 = (float)xv[1], x2 = (float)xv[2], x3 = (float)xv[3];
  float s = x0 + x1 + x2 + x3;
  float q = x0 * x0 + x1 * x1 + x2 * x2 + x3 * x3;
#pragma unroll
  for (int off = 32; off > 0; off >>= 1) {
    s += __shfl_xor(s, off, 64);
    q += __shfl_xor(q, off, 64);
  }
  __shared__ float ss[4], qs[4];
  if ((tid & 63) == 0) { ss[tid >> 6] = s; qs[tid >> 6] = q; }
  __syncthreads();
  s = ss[0] + ss[1] + ss[2] + ss[3];
  q = qs[0] + qs[1] + qs[2] + qs[3];
  float mean = s * (1.f / 1024.f);
  float var = q * (1.f / 1024.f) - mean * mean;
  float rstd = rsqrtf(var + 1e-5f);
  float4 g = reinterpret_cast<const float4*>(gamma)[tid];
  float4 bt = reinterpret_cast<const float4*>(beta)[tid];
  float4 o;
  o.x = (x0 - mean) * rstd * g.x + bt.x;
  o.y = (x1 - mean) * rstd * g.y + bt.y;
  o.z = (x2 - mean) * rstd * g.z + bt.z;
  o.w = (x3 - mean) * rstd * g.w + bt.w;
  reinterpret_cast<float4*>(out + (size_t)row * 1024)[tid] = o;
}

// ---------------------------------------------------------------- launch
extern "C" void kernel_launch(void* const* d_in, const int* in_sizes, int n_in,
                              void* d_out, int out_size, void* d_ws, size_t ws_size,
                              hipStream_t stream) {
  (void)in_sizes; (void)n_in; (void)out_size;
  const float* q       = (const float*)d_in[0];
  const float* k       = (const float*)d_in[1];
  const float* v       = (const float*)d_in[2];
  const float* w_qs    = (const float*)d_in[3];
  const float* w_ks    = (const float*)d_in[4];
  const float* w_vs    = (const float*)d_in[5];
  const float* fc_w    = (const float*)d_in[6];
  const float* resid_w = (const float*)d_in[7];
  const float* resid_b = (const float*)d_in[8];
  const float* ln_g    = (const float*)d_in[9];
  const float* ln_b    = (const float*)d_in[10];
  float* out = (float*)d_out;
  char* ws = (char*)d_ws;

  if (ws_size < (size_t)122716160) return;  // need ~117 MB

  bf16_t* qb   = (bf16_t*)(ws + 0);
  bf16_t* kb   = (bf16_t*)(ws + 12582912);
  bf16_t* vb   = (bf16_t*)(ws + 29360128);
  bf16_t* Y    = (bf16_t*)(ws + 12582912);  // aliases kb+vb (dead after projections)
  bf16_t* wqsT = (bf16_t*)(ws + 46137344);
  bf16_t* wksT = (bf16_t*)(ws + 47710208);
  bf16_t* wvsT = (bf16_t*)(ws + 49807360);
  bf16_t* fcwT = (bf16_t*)(ws + 51904512);
  bf16_t* rswT = (bf16_t*)(ws + 54001664);
  bf16_t* Qp   = (bf16_t*)(ws + 55574528);
  bf16_t* Kp   = (bf16_t*)(ws + 72351744);
  bf16_t* Aout = (bf16_t*)(ws + 89128960);
  bf16_t* VtT  = (bf16_t*)(ws + 105906176);
  float*  Vsm  = (float*)(ws + 122683392);

  k_prep<<<3200, 256, 0, stream>>>(q, k, v, w_qs, w_ks, w_vs, fc_w, resid_w,
                                   qb, kb, vb, wqsT, wksT, wvsT, fcwT, rswT, Vsm);
  // Q pre-scale: 1/8 * log2(e) so scores feed 2^x directly
  k_gemm_proj<<<1536, 256, 0, stream>>>(qb, wqsT, Qp, kb, wksT, Kp, vb, wvsT, VtT,
                                        Vsm, 0.18033688011f);
  k_attn<<<512, 512, 0, stream>>>(Qp, Kp, VtT, Vsm, Aout);
  k_gemm_final<<<512, 256, 0, stream>>>(Aout, fcwT, 1024, qb, rswT, 768, resid_b, Y, 1024);
  k_ln<<<8192, 256, 0, stream>>>(Y, ln_g, ln_b, out);
}

// Round 10
// 177.231 us; speedup vs baseline: 1.3317x; 1.0089x over previous
//
#include <hip/hip_runtime.h>

typedef __bf16 bf16_t;
typedef __bf16 bf16x8 __attribute__((ext_vector_type(8)));
typedef __bf16 bf16x4 __attribute__((ext_vector_type(4)));
typedef float  f32x4  __attribute__((ext_vector_type(4)));

#if __has_builtin(__builtin_amdgcn_exp2f)
#define EXP2(x) __builtin_amdgcn_exp2f(x)
#else
#define EXP2(x) exp2f(x)
#endif

#define DEVFN __device__ __forceinline__

DEVFN void gl_lds16(void* lds_base, const void* gsrc) {
  __builtin_amdgcn_global_load_lds(
      (const __attribute__((address_space(1))) void*)gsrc,
      (__attribute__((address_space(3))) void*)lds_base, 16, 0, 0);
}

// ---------------------------------------------------------------- prep:
// weight transposes (bid<1152) + q/k/v f32->bf16 converts (+ Vsum zero)
__global__ __launch_bounds__(256) void k_prep(
    const float* __restrict__ q, const float* __restrict__ k, const float* __restrict__ v,
    const float* __restrict__ w_qs, const float* __restrict__ w_ks,
    const float* __restrict__ w_vs, const float* __restrict__ fc_w,
    const float* __restrict__ resid_w,
    bf16_t* __restrict__ qb, bf16_t* __restrict__ kb, bf16_t* __restrict__ vb,
    bf16_t* __restrict__ wqsT, bf16_t* __restrict__ wksT, bf16_t* __restrict__ wvsT,
    bf16_t* __restrict__ fcwT, bf16_t* __restrict__ rswT,
    float* __restrict__ Vs) {
  __shared__ float t[64][65];
  int bid = blockIdx.x;
  if (bid < 1152) {
    const float* w; bf16_t* wt; int K;
    if (bid < 192)      { w = w_qs;    wt = wqsT; K = 768; }
    else if (bid < 448) { w = w_ks;    wt = wksT; K = 1024; bid -= 192; }
    else if (bid < 704) { w = w_vs;    wt = wvsT; K = 1024; bid -= 448; }
    else if (bid < 960) { w = fc_w;    wt = fcwT; K = 1024; bid -= 704; }
    else                { w = resid_w; wt = rswT; K = 768;  bid -= 960; }
    const int bk = (bid >> 4) << 6;
    const int bn = (bid & 15) << 6;
    const int rr = threadIdx.x >> 4;
    const int cc = (threadIdx.x & 15) << 2;
#pragma unroll
    for (int i = 0; i < 4; ++i) {
      int r = i * 16 + rr;
      float4 vv = *reinterpret_cast<const float4*>(&w[(size_t)(bk + r) * 1024 + bn + cc]);
      t[r][cc] = vv.x; t[r][cc + 1] = vv.y; t[r][cc + 2] = vv.z; t[r][cc + 3] = vv.w;
    }
    __syncthreads();
#pragma unroll
    for (int i = 0; i < 4; ++i) {
      int n = i * 16 + rr;
      bf16x4 o;
      o[0] = (bf16_t)t[cc][n];     o[1] = (bf16_t)t[cc + 1][n];
      o[2] = (bf16_t)t[cc + 2][n]; o[3] = (bf16_t)t[cc + 3][n];
      *reinterpret_cast<bf16x4*>(&wt[(size_t)(bn + n) * K + bk + cc]) = o;
    }
    return;
  }
  bid -= 1152;
  if (bid == 0) {
    for (int j = threadIdx.x; j < 8192; j += 256) Vs[j] = 0.f;  // atomic target
  }
  const int NQ = 1572864, NK = 2097152, NT = NQ + 2 * NK;
  int stride = (gridDim.x - 1152) * 256;
  for (int i = bid * 256 + threadIdx.x; i < NT; i += stride) {
    const float* src; bf16_t* dst; int off;
    if (i < NQ)           { src = q; dst = qb; off = i; }
    else if (i < NQ + NK) { src = k; dst = kb; off = i - NQ; }
    else                  { src = v; dst = vb; off = i - NQ - NK; }
    float4 vv = reinterpret_cast<const float4*>(src)[off];
    bf16x4 o;
    o[0] = (bf16_t)vv.x; o[1] = (bf16_t)vv.y; o[2] = (bf16_t)vv.z; o[3] = (bf16_t)vv.w;
    reinterpret_cast<bf16x4*>(dst)[off] = o;
  }
}

// ---------------------------------------------------------------- GEMM tile compute (double-buffered)
DEVFN void gemm_tiles(const bf16_t* __restrict__ A, const bf16_t* __restrict__ Bt,
                      int K, int m0, int n0, bf16_t (*sm)[4096], f32x4 (&acc)[4][4]) {
  const int lane = threadIdx.x & 63;
  const int wv = threadIdx.x >> 6;
  const int wr = (wv >> 1) * 64, wc = (wv & 1) * 64;
  const int lr = lane & 15, lk = lane >> 4;
  const int so0 = wv * 2048 + lane * 16;
  const int so1 = so0 + 1024;
  const int r0 = so0 >> 6, r1 = so1 >> 6;
  const int c0 = ((((so0 >> 4) & 3) ^ (r0 & 3)) << 4);
  const int c1 = ((((so1 >> 4) & 3) ^ (r1 & 3)) << 4);
  const int asw = ((lk ^ (lr & 3)) << 4);
  const char* Apc = (const char*)A;
  const char* Btc = (const char*)Bt;
  f32x4 zro = {0.f, 0.f, 0.f, 0.f};
#pragma unroll
  for (int i = 0; i < 4; ++i)
#pragma unroll
    for (int j = 0; j < 4; ++j) acc[i][j] = zro;

  const int nk = K >> 5;
  auto stage = [&](int buf, int t) {
    gl_lds16((char*)sm[buf] + wv * 2048,        Apc + ((size_t)(m0 + r0) * K + t * 32) * 2 + c0);
    gl_lds16((char*)sm[buf] + wv * 2048 + 1024, Apc + ((size_t)(m0 + r1) * K + t * 32) * 2 + c1);
    gl_lds16((char*)sm[2 + buf] + wv * 2048,        Btc + ((size_t)(n0 + r0) * K + t * 32) * 2 + c0);
    gl_lds16((char*)sm[2 + buf] + wv * 2048 + 1024, Btc + ((size_t)(n0 + r1) * K + t * 32) * 2 + c1);
  };
  stage(0, 0);
  __syncthreads();
  for (int t = 0; t < nk; ++t) {
    const int cur = t & 1;
    if (t + 1 < nk) stage(cur ^ 1, t + 1);
    const char* AsB = (const char*)sm[cur];
    const char* BsB = (const char*)sm[2 + cur];
    bf16x8 af[4], bfr[4];
#pragma unroll
    for (int i = 0; i < 4; ++i)
      af[i] = *(const bf16x8*)(AsB + (wr + i * 16 + lr) * 64 + asw);
#pragma unroll
    for (int j = 0; j < 4; ++j)
      bfr[j] = *(const bf16x8*)(BsB + (wc + j * 16 + lr) * 64 + asw);
#pragma unroll
    for (int i = 0; i < 4; ++i)
#pragma unroll
      for (int j = 0; j < 4; ++j)
        acc[i][j] = __builtin_amdgcn_mfma_f32_16x16x32_bf16(af[i], bfr[j], acc[i][j], 0, 0, 0);
    __syncthreads();
  }
}

// fused Q/K/V projections: 1536 blocks, 512 per projection.
// Route 0 = V (slowest: fused transpose epilogue) so its blocks dispatch first.
__global__ __launch_bounds__(256) void k_gemm_proj(
    const bf16_t* __restrict__ qb, const bf16_t* __restrict__ wqsT, bf16_t* __restrict__ Qp,
    const bf16_t* __restrict__ kb, const bf16_t* __restrict__ wksT, bf16_t* __restrict__ Kp,
    const bf16_t* __restrict__ vb, const bf16_t* __restrict__ wvsT, bf16_t* __restrict__ Vt,
    float* __restrict__ Vsum, float qscale) {
  __shared__ bf16_t sm[4][4096];
  const int bid = blockIdx.x;
  const int route = bid >> 9;          // 0:V 1:K 2:Q
  const int sbid = bid & 511;
  const int wg = (sbid & 7) * 64 + (sbid >> 3);   // XCD-grouped
  const int tn = 8;                                // N=1024 → 8 col tiles
  const int m0 = (wg / tn) << 7;
  const int n0 = (wg % tn) << 7;
  const int lane = threadIdx.x & 63;
  const int wv = threadIdx.x >> 6;
  const int wr = (wv >> 1) * 64, wc = (wv & 1) * 64;
  const int lr = lane & 15, lk = lane >> 4;
  f32x4 acc[4][4];

  if (route == 0) {
    gemm_tiles(vb, wvsT, 1024, m0, n0, sm, acc);
    // acc[i][j][r] = Vproj[kv = m0+wr+i*16+lk*4+r][n = n0+wc+j*16+lr]
    const int b = m0 >> 10;
    const int h0 = n0 >> 6;
    const int kt0 = (m0 & 1023) >> 6;
    const int h_local = wc >> 6, kt_local = wr >> 6;   // wave-constant
    char* tl = (char*)sm + (h_local * 2 + kt_local) * 8192;  // wave-private tile
#pragma unroll
    for (int i = 0; i < 4; ++i) {
      const int kvl = i * 16 + lk * 4;
      const int csel = kvl >> 3;
      const int hoff = (kvl & 7) * 2;
#pragma unroll
      for (int j = 0; j < 4; ++j) {
        const int d = j * 16 + lr;
        bf16x4 pw;
#pragma unroll
        for (int r = 0; r < 4; ++r) pw[r] = (bf16_t)acc[i][j][r];
        *reinterpret_cast<bf16x4*>(tl + d * 128 + ((csel ^ (d & 7)) << 4) + hoff) = pw;
      }
    }
    {
      const size_t gbase = (size_t)(b * 16 + h0 + h_local) * 131072 +
                           (size_t)(kt0 + kt_local) * 8192;
#pragma unroll
      for (int it = 0; it < 8; ++it)
        *reinterpret_cast<uint4*>((char*)Vt + gbase + it * 1024 + lane * 16) =
            *reinterpret_cast<const uint4*>(tl + it * 1024 + lane * 16);
    }
    const int h = h0 + h_local;
#pragma unroll
    for (int j = 0; j < 4; ++j) {
      float s = 0.f;
#pragma unroll
      for (int i = 0; i < 4; ++i)
#pragma unroll
        for (int r = 0; r < 4; ++r) s += acc[i][j][r];
      s += __shfl_xor(s, 16, 64);
      s += __shfl_xor(s, 32, 64);
      if (lane < 16)
        atomicAdd(&Vsum[(b * 16 + h) * 64 + j * 16 + lane], s);
    }
  } else if (route == 1) {
    gemm_tiles(kb, wksT, 1024, m0, n0, sm, acc);
#pragma unroll
    for (int i = 0; i < 4; ++i)
#pragma unroll
      for (int j = 0; j < 4; ++j)
#pragma unroll
        for (int r = 0; r < 4; ++r)
          Kp[(size_t)(m0 + wr + i * 16 + lk * 4 + r) * 1024 + n0 + wc + j * 16 + lr] =
              (bf16_t)acc[i][j][r];
  } else {
    gemm_tiles(qb, wqsT, 768, m0, n0, sm, acc);
#pragma unroll
    for (int i = 0; i < 4; ++i)
#pragma unroll
      for (int j = 0; j < 4; ++j)
#pragma unroll
        for (int r = 0; r < 4; ++r)
          Qp[(size_t)(m0 + wr + i * 16 + lk * 4 + r) * 1024 + n0 + wc + j * 16 + lr] =
              (bf16_t)(acc[i][j][r] * qscale);
  }
}

// Y[M,N] bf16 = A1*B1t^T + A2*B2t^T + bias — one continuous K-loop over both
// phases (stage pointers switch at nk1; acc accumulates across, sum is additive)
__global__ __launch_bounds__(256) void k_gemm_final(
    const bf16_t* __restrict__ A1, const bf16_t* __restrict__ B1t, int K1,
    const bf16_t* __restrict__ A2, const bf16_t* __restrict__ B2t, int K2,
    const float* __restrict__ bias, bf16_t* __restrict__ Y, int N) {
  __shared__ bf16_t sm[4][4096];
  const int bpx = gridDim.x >> 3;
  const int wg = (blockIdx.x & 7) * bpx + (blockIdx.x >> 3);
  const int tn = N >> 7;
  const int m0 = (wg / tn) << 7;
  const int n0 = (wg % tn) << 7;
  const int lane = threadIdx.x & 63;
  const int wv = threadIdx.x >> 6;
  const int wr = (wv >> 1) * 64, wc = (wv & 1) * 64;
  const int lr = lane & 15, lk = lane >> 4;
  const int so0 = wv * 2048 + lane * 16;
  const int so1 = so0 + 1024;
  const int r0 = so0 >> 6, r1 = so1 >> 6;
  const int c0 = ((((so0 >> 4) & 3) ^ (r0 & 3)) << 4);
  const int c1 = ((((so1 >> 4) & 3) ^ (r1 & 3)) << 4);
  const int asw = ((lk ^ (lr & 3)) << 4);
  f32x4 zro = {0.f, 0.f, 0.f, 0.f};
  f32x4 acc[4][4];
#pragma unroll
  for (int i = 0; i < 4; ++i)
#pragma unroll
    for (int j = 0; j < 4; ++j) acc[i][j] = zro;

  const int nk1 = K1 >> 5;
  const int nkt = (K1 + K2) >> 5;
  auto stage = [&](int buf, int t) {
    const char* Apc; const char* Btc; int K, tt;
    if (t < nk1) { Apc = (const char*)A1; Btc = (const char*)B1t; K = K1; tt = t; }
    else         { Apc = (const char*)A2; Btc = (const char*)B2t; K = K2; tt = t - nk1; }
    gl_lds16((char*)sm[buf] + wv * 2048,        Apc + ((size_t)(m0 + r0) * K + tt * 32) * 2 + c0);
    gl_lds16((char*)sm[buf] + wv * 2048 + 1024, Apc + ((size_t)(m0 + r1) * K + tt * 32) * 2 + c1);
    gl_lds16((char*)sm[2 + buf] + wv * 2048,        Btc + ((size_t)(n0 + r0) * K + tt * 32) * 2 + c0);
    gl_lds16((char*)sm[2 + buf] + wv * 2048 + 1024, Btc + ((size_t)(n0 + r1) * K + tt * 32) * 2 + c1);
  };
  stage(0, 0);
  __syncthreads();
  for (int t = 0; t < nkt; ++t) {
    const int cur = t & 1;
    if (t + 1 < nkt) stage(cur ^ 1, t + 1);
    const char* AsB = (const char*)sm[cur];
    const char* BsB = (const char*)sm[2 + cur];
    bf16x8 af[4], bfr[4];
#pragma unroll
    for (int i = 0; i < 4; ++i)
      af[i] = *(const bf16x8*)(AsB + (wr + i * 16 + lr) * 64 + asw);
#pragma unroll
    for (int j = 0; j < 4; ++j)
      bfr[j] = *(const bf16x8*)(BsB + (wc + j * 16 + lr) * 64 + asw);
#pragma unroll
    for (int i = 0; i < 4; ++i)
#pragma unroll
      for (int j = 0; j < 4; ++j)
        acc[i][j] = __builtin_amdgcn_mfma_f32_16x16x32_bf16(af[i], bfr[j], acc[i][j], 0, 0, 0);
    __syncthreads();
  }
#pragma unroll
  for (int i = 0; i < 4; ++i)
#pragma unroll
    for (int j = 0; j < 4; ++j) {
      float bv = bias[n0 + wc + j * 16 + lr];
#pragma unroll
      for (int r = 0; r < 4; ++r)
        Y[(size_t)(m0 + wr + i * 16 + lk * 4 + r) * N + n0 + wc + j * 16 + lr] =
            (bf16_t)(acc[i][j][r] + bv);
    }
}

// ---------------------------------------------------------------- attention (unchanged from r9)
__global__ __launch_bounds__(512) void k_attn(
    const bf16_t* __restrict__ Qp, const bf16_t* __restrict__ Kp,
    const bf16_t* __restrict__ Vt, const float* __restrict__ Vsum,
    bf16_t* __restrict__ Aout) {
  const int bid = blockIdx.x;
  const int wgid = (bid & 7) * 64 + (bid >> 3);   // XCD-grouping, 512 blocks
  const int qg = wgid & 3;
  const int bh = wgid >> 2;
  const int b = bh >> 4, h = bh & 15;
  __shared__ bf16_t Ks[2][4096];
  __shared__ bf16_t Vs[2][4096];
  const int tid = threadIdx.x;
  const int lane = tid & 63;
  const int wv = tid >> 6;
  const int lr = lane & 15, lk = lane >> 4;
  const int stb = (wv >> 2) * 2;
  const int wrow = (wv & 3) * 16;

  const int o = tid * 16;
  const int row = o >> 7;
  const int sc = ((((o >> 4) & 7) ^ (row & 7)) << 4);
  const int srow = (row & 0x23) | ((row & 0x0C) << 1) | ((row & 0x10) >> 2);

  const char* Ksrc  = (const char*)(Kp + ((size_t)(b * 1024 + srow)) * 1024 + h * 64) + sc;
  const char* Vtile = (const char*)Vt + (size_t)bh * 131072 + o;

  gl_lds16((char*)&Ks[0][0] + o, Ksrc);
  gl_lds16((char*)&Vs[0][0] + o, Vtile);

  bf16x8 qa[2][2];
#pragma unroll
  for (int stl = 0; stl < 2; ++stl) {
    const char* qsrc = (const char*)(Qp +
        ((size_t)(b * 1024 + qg * 256 + (stb + stl) * 64 + wrow + lr)) * 1024 + h * 64);
    qa[stl][0] = *(const bf16x8*)(qsrc + lk * 16);
    qa[stl][1] = *(const bf16x8*)(qsrc + 64 + lk * 16);
  }
  __syncthreads();

  const int kb0 = lr * 128 + ((lk ^ (lr & 7)) << 4);
  const int kb1 = lr * 128 + (((4 + lk) ^ (lr & 7)) << 4);

  f32x4 zro = {0.f, 0.f, 0.f, 0.f};
  f32x4 oacc[2][4];
  f32x4 sum[2];
#pragma unroll
  for (int stl = 0; stl < 2; ++stl) {
    sum[stl] = zro;
#pragma unroll
    for (int g = 0; g < 4; ++g) oacc[stl][g] = zro;
  }
  bf16x8 ones8;
#pragma unroll
  for (int j = 0; j < 8; ++j) ones8[j] = (bf16_t)1.0f;

  for (int kt = 0; kt < 16; ++kt) {
    const int cur = kt & 1;
    const char* KsB = (const char*)&Ks[cur][0];
    const char* VsB = (const char*)&Vs[cur][0];
    if (kt < 15) {
      gl_lds16((char*)&Ks[cur ^ 1][0] + o, Ksrc + (size_t)(kt + 1) * 131072);
      gl_lds16((char*)&Vs[cur ^ 1][0] + o, Vtile + (size_t)(kt + 1) * 8192);
    }

    f32x4 sacc[2][4];
#pragma unroll
    for (int stl = 0; stl < 2; ++stl)
#pragma unroll
      for (int g = 0; g < 4; ++g) sacc[stl][g] = zro;
    {
      bf16x8 kf[4];
#pragma unroll
      for (int g = 0; g < 4; ++g) kf[g] = *(const bf16x8*)(KsB + kb0 + g * 2048);
#pragma unroll
      for (int stl = 0; stl < 2; ++stl)
#pragma unroll
        for (int g = 0; g < 4; ++g)
          sacc[stl][g] = __builtin_amdgcn_mfma_f32_16x16x32_bf16(kf[g], qa[stl][0], sacc[stl][g], 0, 0, 0);
#pragma unroll
      for (int g = 0; g < 4; ++g) kf[g] = *(const bf16x8*)(KsB + kb1 + g * 2048);
#pragma unroll
      for (int stl = 0; stl < 2; ++stl)
#pragma unroll
        for (int g = 0; g < 4; ++g)
          sacc[stl][g] = __builtin_amdgcn_mfma_f32_16x16x32_bf16(kf[g], qa[stl][1], sacc[stl][g], 0, 0, 0);
    }

    bf16x8 pa[2][2];
#pragma unroll
    for (int stl = 0; stl < 2; ++stl)
#pragma unroll
      for (int c = 0; c < 2; ++c) {
        bf16x8 pw;
#pragma unroll
        for (int r = 0; r < 4; ++r) {
          pw[r]     = (bf16_t)EXP2(sacc[stl][2 * c][r]);
          pw[4 + r] = (bf16_t)EXP2(sacc[stl][2 * c + 1][r]);
        }
        pa[stl][c] = pw;
      }

#pragma unroll
    for (int c = 0; c < 2; ++c) {
      const int vb = (c == 0) ? kb0 : kb1;
      bf16x8 vf[4];
#pragma unroll
      for (int gd = 0; gd < 4; ++gd)
        vf[gd] = *(const bf16x8*)(VsB + vb + gd * 2048);
#pragma unroll
      for (int stl = 0; stl < 2; ++stl) {
        sum[stl] = __builtin_amdgcn_mfma_f32_16x16x32_bf16(pa[stl][c], ones8, sum[stl], 0, 0, 0);
#pragma unroll
        for (int gd = 0; gd < 4; ++gd)
          oacc[stl][gd] = __builtin_amdgcn_mfma_f32_16x16x32_bf16(pa[stl][c], vf[gd], oacc[stl][gd], 0, 0, 0);
      }
    }
    __syncthreads();
  }

  float vs_d[4];
#pragma unroll
  for (int gd = 0; gd < 4; ++gd) vs_d[gd] = Vsum[bh * 64 + gd * 16 + lr];
#pragma unroll
  for (int stl = 0; stl < 2; ++stl) {
    float inv[4];
#pragma unroll
    for (int r = 0; r < 4; ++r) inv[r] = 1.0f / sum[stl][r];
#pragma unroll
    for (int gd = 0; gd < 4; ++gd)
#pragma unroll
      for (int r = 0; r < 4; ++r) {
        int d = gd * 16 + lr;
        int qrow = qg * 256 + (stb + stl) * 64 + wrow + lk * 4 + r;
        float attnv = oacc[stl][gd][r] * inv[r];
        float val = (vs_d[gd] - attnv) * (1.0f / 1023.0f);
        Aout[((size_t)(b * 1024 + qrow)) * 1024 + h * 64 + d] = (bf16_t)val;
      }
  }
}

// ---------------------------------------------------------------- layernorm (bf16 input)
__global__ __launch_bounds__(256) void k_ln(
    const bf16_t* __restrict__ Y, const float* __restrict__ gamma,
    const float* __restrict__ beta, float* __restrict__ out) {
  const int row = blockIdx.x, tid = threadIdx.x;
  bf16x4 xv = reinterpret_cast<const bf16x4*>(Y + (size_t)row * 1024)[tid];
  float x0 = (float)xv[0], x1 = (float)xv[1], x2 = (float)xv[2], x3 = (float)xv[3];
  float s = x0 + x1 + x2 + x3;
  float q = x0 * x0 + x1 * x1 + x2 * x2 + x3 * x3;
#pragma unroll
  for (int off = 32; off > 0; off >>= 1) {
    s += __shfl_xor(s, off, 64);
    q += __shfl_xor(q, off, 64);
  }
  __shared__ float ss[4], qs[4];
  if ((tid & 63) == 0) { ss[tid >> 6] = s; qs[tid >> 6] = q; }
  __syncthreads();
  s = ss[0] + ss[1] + ss[2] + ss[3];
  q = qs[0] + qs[1] + qs[2] + qs[3];
  float mean = s * (1.f / 1024.f);
  float var = q * (1.f / 1024.f) - mean * mean;
  float rstd = rsqrtf(var + 1e-5f);
  float4 g = reinterpret_cast<const float4*>(gamma)[tid];
  float4 bt = reinterpret_cast<const float4*>(beta)[tid];
  float4 o;
  o.x = (x0 - mean) * rstd * g.x + bt.x;
  o.y = (x1 - mean) * rstd * g.y + bt.y;
  o.z = (x2 - mean) * rstd * g.z + bt.z;
  o.w = (x3 - mean) * rstd * g.w + bt.w;
  reinterpret_cast<float4*>(out + (size_t)row * 1024)[tid] = o;
}

// ---------------------------------------------------------------- launch
extern "C" void kernel_launch(void* const* d_in, const int* in_sizes, int n_in,
                              void* d_out, int out_size, void* d_ws, size_t ws_size,
                              hipStream_t stream) {
  (void)in_sizes; (void)n_in; (void)out_size;
  const float* q       = (const float*)d_in[0];
  const float* k       = (const float*)d_in[1];
  const float* v       = (const float*)d_in[2];
  const float* w_qs    = (const float*)d_in[3];
  const float* w_ks    = (const float*)d_in[4];
  const float* w_vs    = (const float*)d_in[5];
  const float* fc_w    = (const float*)d_in[6];
  const float* resid_w = (const float*)d_in[7];
  const float* resid_b = (const float*)d_in[8];
  const float* ln_g    = (const float*)d_in[9];
  const float* ln_b    = (const float*)d_in[10];
  float* out = (float*)d_out;
  char* ws = (char*)d_ws;

  if (ws_size < (size_t)122716160) return;  // need ~117 MB

  bf16_t* qb   = (bf16_t*)(ws + 0);
  bf16_t* kb   = (bf16_t*)(ws + 12582912);
  bf16_t* vb   = (bf16_t*)(ws + 29360128);
  bf16_t* Y    = (bf16_t*)(ws + 12582912);  // aliases kb+vb (dead after projections)
  bf16_t* wqsT = (bf16_t*)(ws + 46137344);
  bf16_t* wksT = (bf16_t*)(ws + 47710208);
  bf16_t* wvsT = (bf16_t*)(ws + 49807360);
  bf16_t* fcwT = (bf16_t*)(ws + 51904512);
  bf16_t* rswT = (bf16_t*)(ws + 54001664);
  bf16_t* Qp   = (bf16_t*)(ws + 55574528);
  bf16_t* Kp   = (bf16_t*)(ws + 72351744);
  bf16_t* Aout = (bf16_t*)(ws + 89128960);
  bf16_t* VtT  = (bf16_t*)(ws + 105906176);
  float*  Vsm  = (float*)(ws + 122683392);

  k_prep<<<3200, 256, 0, stream>>>(q, k, v, w_qs, w_ks, w_vs, fc_w, resid_w,
                                   qb, kb, vb, wqsT, wksT, wvsT, fcwT, rswT, Vsm);
  // Q pre-scale: 1/8 * log2(e) so scores feed 2^x directly
  k_gemm_proj<<<1536, 256, 0, stream>>>(qb, wqsT, Qp, kb, wksT, Kp, vb, wvsT, VtT,
                                        Vsm, 0.18033688011f);
  k_attn<<<512, 512, 0, stream>>>(Qp, Kp, VtT, Vsm, Aout);
  k_gemm_final<<<512, 256, 0, stream>>>(Aout, fcwT, 1024, qb, rswT, 768, resid_b, Y, 1024);
  k_ln<<<8192, 256, 0, stream>>>(Y, ln_g, ln_b, out);
}